// Round 11
// baseline (233.751 us; speedup 1.0000x reference)
//
#include <hip/hip_runtime.h>
#include <hip/hip_bf16.h>
#include <hip/hip_cooperative_groups.h>

namespace cg = cooperative_groups;

// Problem constants (fixed by reference setup_inputs)
constexpr int B_ = 8;
constexpr int N_ = 16;
constexpr int H_ = 368;
constexpr int W_ = 640;
constexpr int P_ = H_ * W_;          // 235520 pixels per image
constexpr int C_ = 12;               // instance ids 1..12
constexpr float MARGIN_VAR_ = 0.5f;
constexpr float MARGIN_DIST_ = 3.0f;

// Workspace layout (floats): sums + counts
constexpr int OFF_SUMS = 0;                      // [B][C][N] feature sums
constexpr int OFF_CNT  = OFF_SUMS + B_*C_*N_;    // [B][C]    pixel counts
constexpr int WS_FLOATS = OFF_CNT + B_*C_;       // 1632 floats

constexpr int TPB   = 256;
constexpr int CHUNK = 2048;            // pixels per block
constexpr int BPI   = P_ / CHUNK;      // 115 (exact)
constexpr int NB    = B_ * BPI;        // 920 blocks (<= 1024 co-resident @4/CU)

constexpr int SUB = 512;               // staging subtile (pixels)
constexpr int RS  = 520;               // LDS row stride in shorts (512 + 8 pad)

typedef short bf16x8 __attribute__((ext_vector_type(8)));   // 8 bf16 (4 VGPR)
typedef float f32x4  __attribute__((ext_vector_type(4)));   // MFMA accumulator

union FragU { int4 i; bf16x8 v; };

__device__ __forceinline__ short f2bf(float f) {
    __hip_bfloat16 h = __float2bfloat16(f);
    return __builtin_bit_cast(short, h);
}

__device__ __forceinline__ int pack_bf2(float x, float y) {
    const unsigned lo = (unsigned short)f2bf(x);
    const unsigned hi = (unsigned short)f2bf(y);
    return (int)(lo | (hi << 16));
}

// ---------------------------------------------------------------------------
// PHASE 0: accumulate only.  PHASE 1: finalize only.  PHASE 2: fused w/ grid
// sync (cooperative).  Low register pressure (~80 VGPR): no kept tile.
// ---------------------------------------------------------------------------
template<int PHASE>
__global__ __launch_bounds__(TPB, 4) void k_fused(const float* __restrict__ feat,
                                                  const int* __restrict__ gt,
                                                  float* __restrict__ ws,
                                                  float* __restrict__ out) {
    __shared__ int   s_lab[CHUNK];         // 8 KB
    __shared__ short s_feat[N_ * RS];      // 16.6 KB bf16 subtile (512 px)
    __shared__ float s_fin[4][256];        // 4 KB
    __shared__ float s_red[4][C_];
    __shared__ float s_cen[C_][N_ + 1];
    __shared__ float s_w[C_];
    __shared__ float s_cntv[B_ * C_];
    __shared__ float red[TPB];
    __shared__ float wsum[TPB / 64];

    const int tid  = threadIdx.x;
    const int lane = tid & 63, wid = tid >> 6;
    const int b     = blockIdx.x / BPI;
    const int chunk = blockIdx.x % BPI;
    const int base  = chunk * CHUNK;

    const int*   __restrict__ gb = gt   + (size_t)b * P_ + base;
    const float* __restrict__ fb = feat + (size_t)b * N_ * P_ + base;

    if (PHASE != 1) {
        // ================= Phase A: sums + counts =================
        if (blockIdx.x == 0 && tid == 0) out[0] = 0.f;

        const int4 la = ((const int4*)gb)[tid];
        const int4 lc = ((const int4*)gb)[256 + tid];
        ((int4*)s_lab)[tid]       = la;
        ((int4*)s_lab)[256 + tid] = lc;

        float cnt[C_];
        #pragma unroll
        for (int c = 0; c < C_; ++c) {
            cnt[c] = ((la.x == c+1) ? 1.f : 0.f) + ((la.y == c+1) ? 1.f : 0.f)
                   + ((la.z == c+1) ? 1.f : 0.f) + ((la.w == c+1) ? 1.f : 0.f)
                   + ((lc.x == c+1) ? 1.f : 0.f) + ((lc.y == c+1) ? 1.f : 0.f)
                   + ((lc.z == c+1) ? 1.f : 0.f) + ((lc.w == c+1) ? 1.f : 0.f);
        }
        #pragma unroll
        for (int off = 32; off > 0; off >>= 1) {
            #pragma unroll
            for (int c = 0; c < C_; ++c) cnt[c] += __shfl_xor(cnt[c], off, 64);
        }
        if (lane == 0) {
            #pragma unroll
            for (int c = 0; c < C_; ++c) s_red[wid][c] = cnt[c];
        }

        // prefetch subtile 0 (8 coalesced dwordx4 in flight across the barrier)
        const int h   = tid >> 7;          // channel parity
        const int p4  = tid & 127;         // px4 slot within subtile
        float4 tr[8];
        #pragma unroll
        for (int j = 0; j < 8; ++j)
            tr[j] = *(const float4*)(fb + (size_t)(j * 2 + h) * P_ + p4 * 4);

        __syncthreads();   // s_lab + s_red visible
        if (tid < C_) {
            const float t = s_red[0][tid] + s_red[1][tid] + s_red[2][tid] + s_red[3][tid];
            atomicAdd(&ws[OFF_CNT + b * C_ + tid], t);
        }

        const int n   = lane & 15;          // class-1 (A row) / channel (B col)
        const int cls = n + 1;
        const int ko  = (lane >> 4) * 8;    // k-octet within 32-px chunk

        f32x4 acc = {0.f, 0.f, 0.f, 0.f};

        #pragma unroll
        for (int s = 0; s < 4; ++s) {
            if (s > 0) __syncthreads();     // all waves done reading s_feat[s-1]
            #pragma unroll
            for (int j = 0; j < 8; ++j) {
                int2 w;
                w.x = pack_bf2(tr[j].x, tr[j].y);
                w.y = pack_bf2(tr[j].z, tr[j].w);
                *(int2*)(s_feat + (j * 2 + h) * RS + p4 * 4) = w;
            }
            __syncthreads();                // subtile s staged
            if (s < 3) {                    // prefetch s+1 during MFMA
                #pragma unroll
                for (int j = 0; j < 8; ++j)
                    tr[j] = *(const float4*)(fb + (size_t)(j * 2 + h) * P_
                                             + (s + 1) * SUB + p4 * 4);
            }
            #pragma unroll
            for (int k = 0; k < 4; ++k) {
                const int t = wid * 4 + k;
                const int* lp = s_lab + s * SUB + t * 32 + ko;
                const int4 L0 = *(const int4*)(lp);
                const int4 L1 = *(const int4*)(lp + 4);
                FragU au, bu;
                au.i.x = ((L0.x == cls) ? 0x3F80 : 0) | ((L0.y == cls) ? 0x3F800000 : 0);
                au.i.y = ((L0.z == cls) ? 0x3F80 : 0) | ((L0.w == cls) ? 0x3F800000 : 0);
                au.i.z = ((L1.x == cls) ? 0x3F80 : 0) | ((L1.y == cls) ? 0x3F800000 : 0);
                au.i.w = ((L1.z == cls) ? 0x3F80 : 0) | ((L1.w == cls) ? 0x3F800000 : 0);
                bu.v = *(const bf16x8*)(s_feat + n * RS + t * 32 + ko);
                acc = __builtin_amdgcn_mfma_f32_16x16x32_bf16(au.v, bu.v, acc, 0, 0, 0);
            }
        }

        __syncthreads();
        #pragma unroll
        for (int r = 0; r < 4; ++r) s_fin[wid][lane * 4 + r] = acc[r];
        __syncthreads();
        {
            const float sv = s_fin[0][tid] + s_fin[1][tid] + s_fin[2][tid] + s_fin[3][tid];
            const int elane = tid >> 2, r = tid & 3;
            const int row = (elane >> 4) * 4 + r;   // class (D row)
            const int col = elane & 15;             // channel (D col)
            if (row < C_)
                atomicAdd(&ws[OFF_SUMS + ((size_t)b * C_ + row) * N_ + col], sv);
        }
    }

    if constexpr (PHASE == 2) {
        cg::this_grid().sync();
    }

    if (PHASE != 0) {
        // ================= Phase B: centers, push, pull =================
        if (tid < B_ * C_) s_cntv[tid] = ws[OFF_CNT + tid];
        __syncthreads();

        float n_inst = 0.f;
        #pragma unroll 8
        for (int i = 0; i < B_ * C_; ++i) n_inst += (s_cntv[i] > 0.f) ? 1.f : 0.f;

        if (tid < C_ * N_) {
            const int c = tid >> 4, nn = tid & 15;
            const float ct = s_cntv[b * C_ + c];
            s_cen[c][nn] = ws[OFF_SUMS + ((size_t)b * C_ + c) * N_ + nn] / fmaxf(ct, 1.f);
        }
        if (tid < C_) {
            const float ct = s_cntv[b * C_ + tid];
            s_w[tid] = (ct > 0.f && n_inst > 0.f) ? 1.0f / (ct * n_inst) : 0.f;
        }
        __syncthreads();

        if (chunk == 0) {
            float ps = 0.f;
            if (tid < C_ * C_) {
                const int i = tid / C_, j = tid % C_;
                if (i != j && s_cntv[b * C_ + i] > 0.f && s_cntv[b * C_ + j] > 0.f) {
                    float sq = 0.f;
                    #pragma unroll
                    for (int nn = 0; nn < N_; ++nn) {
                        const float d = s_cen[i][nn] - s_cen[j][nn];
                        sq += d * d;
                    }
                    ps = fmaxf(2.f * MARGIN_DIST_ - sqrtf(sq), 0.f);
                }
            }
            red[tid] = ps;
            __syncthreads();
            for (int s = TPB / 2; s > 0; s >>= 1) {
                if (tid < s) red[tid] += red[tid + s];
                __syncthreads();
            }
            if (tid == 0) {
                float np = 0.f;
                for (int bb_ = 0; bb_ < B_; ++bb_) {
                    int k = 0;
                    for (int c = 0; c < C_; ++c) k += (s_cntv[bb_ * C_ + c] > 0.f) ? 1 : 0;
                    np += (float)(k * (k - 1));
                }
                if (np > 0.f) atomicAdd(out, red[0] / np);   // DIST_WEIGHT = 1
            }
        }

        // pull: two halves of 1024 px, channel-group pipelined loads
        float acc2 = 0.f;
        #pragma unroll
        for (int hh = 0; hh < 2; ++hh) {
            const int4 lb = ((const int4*)gb)[hh * 256 + tid];
            const float* __restrict__ fh = fb + hh * 1024 + tid * 4;

            float4 va[4], vb[4];
            #pragma unroll
            for (int j = 0; j < 4; ++j) va[j] = *(const float4*)(fh + (size_t)j * P_);
            #pragma unroll
            for (int j = 0; j < 4; ++j) vb[j] = *(const float4*)(fh + (size_t)(4 + j) * P_);

            const bool vx = (lb.x >= 1 && lb.x <= C_);
            const bool vy = (lb.y >= 1 && lb.y <= C_);
            const bool vz = (lb.z >= 1 && lb.z <= C_);
            const bool vw = (lb.w >= 1 && lb.w <= C_);
            const int cx = vx ? lb.x - 1 : 0;
            const int cy = vy ? lb.y - 1 : 0;
            const int cz = vz ? lb.z - 1 : 0;
            const int cw = vw ? lb.w - 1 : 0;

            float sq0 = 0.f, sq1 = 0.f, sq2 = 0.f, sq3 = 0.f;
            auto consume4 = [&](const float4* r, int cb) {
                #pragma unroll
                for (int j = 0; j < 4; ++j) {
                    const int nn = cb + j;
                    const float d0 = r[j].x - s_cen[cx][nn];
                    const float d1 = r[j].y - s_cen[cy][nn];
                    const float d2 = r[j].z - s_cen[cz][nn];
                    const float d3 = r[j].w - s_cen[cw][nn];
                    sq0 += d0 * d0; sq1 += d1 * d1; sq2 += d2 * d2; sq3 += d3 * d3;
                }
            };

            consume4(va, 0);
            #pragma unroll
            for (int j = 0; j < 4; ++j) va[j] = *(const float4*)(fh + (size_t)(8 + j) * P_);
            consume4(vb, 4);
            #pragma unroll
            for (int j = 0; j < 4; ++j) vb[j] = *(const float4*)(fh + (size_t)(12 + j) * P_);
            consume4(va, 8);
            consume4(vb, 12);

            acc2 += fmaxf(sqrtf(sq0) - MARGIN_VAR_, 0.f) * (vx ? s_w[cx] : 0.f);
            acc2 += fmaxf(sqrtf(sq1) - MARGIN_VAR_, 0.f) * (vy ? s_w[cy] : 0.f);
            acc2 += fmaxf(sqrtf(sq2) - MARGIN_VAR_, 0.f) * (vz ? s_w[cz] : 0.f);
            acc2 += fmaxf(sqrtf(sq3) - MARGIN_VAR_, 0.f) * (vw ? s_w[cw] : 0.f);
        }

        #pragma unroll
        for (int off = 32; off > 0; off >>= 1) acc2 += __shfl_down(acc2, off, 64);
        if (lane == 0) wsum[wid] = acc2;
        __syncthreads();
        if (tid == 0) {
            float t = 0.f;
            #pragma unroll
            for (int w = 0; w < TPB / 64; ++w) t += wsum[w];
            atomicAdd(out, t);   // VAR_WEIGHT = 1
        }
    }
}

// ---------------------------------------------------------------------------
extern "C" void kernel_launch(void* const* d_in, const int* in_sizes, int n_in,
                              void* d_out, int out_size, void* d_ws, size_t ws_size,
                              hipStream_t stream) {
    const float* feat = (const float*)d_in[0];
    const int*   gt   = (const int*)d_in[1];
    float* out = (float*)d_out;
    float* ws  = (float*)d_ws;

    (void)hipMemsetAsync(d_ws, 0, WS_FLOATS * sizeof(float), stream);

    void* args[] = { (void*)&feat, (void*)&gt, (void*)&ws, (void*)&out };
    hipError_t e = hipLaunchCooperativeKernel((void*)(&k_fused<2>), dim3(NB),
                                              dim3(TPB), args, 0, stream);
    if (e != hipSuccess) {
        // Fallback: same kernel, two ordinary launches (phase-split).
        k_fused<0><<<dim3(NB), dim3(TPB), 0, stream>>>(feat, gt, ws, out);
        k_fused<1><<<dim3(NB), dim3(TPB), 0, stream>>>(feat, gt, ws, out);
    }
}

// Round 12
// 228.722 us; speedup vs baseline: 1.0220x; 1.0220x over previous
//
#include <hip/hip_runtime.h>
#include <hip/hip_bf16.h>
#include <hip/hip_cooperative_groups.h>

namespace cg = cooperative_groups;

// Problem constants (fixed by reference setup_inputs)
constexpr int B_ = 8;
constexpr int N_ = 16;
constexpr int H_ = 368;
constexpr int W_ = 640;
constexpr int P_ = H_ * W_;          // 235520 pixels per image
constexpr int C_ = 12;               // instance ids 1..12
constexpr float MARGIN_VAR_ = 0.5f;
constexpr float MARGIN_DIST_ = 3.0f;

// Workspace layout (floats): sums + counts
constexpr int OFF_SUMS = 0;                      // [B][C][N] feature sums
constexpr int OFF_CNT  = OFF_SUMS + B_*C_*N_;    // [B][C]    pixel counts
constexpr int WS_FLOATS = OFF_CNT + B_*C_;       // 1632 floats

constexpr int TPB   = 256;
constexpr int CHUNK = 2048;            // pixels per block
constexpr int BPI   = P_ / CHUNK;      // 115 (exact)
constexpr int NB    = B_ * BPI;        // 920 blocks (<= co-residency capacity)

constexpr int SUB = 512;               // staging subtile (pixels)
constexpr int RS  = 520;               // LDS row stride in shorts (512 + 8 pad)

typedef short bf16x8 __attribute__((ext_vector_type(8)));   // 8 bf16 (4 VGPR)
typedef float f32x4  __attribute__((ext_vector_type(4)));   // MFMA accumulator

union FragU { int4 i; bf16x8 v; };

__device__ __forceinline__ short f2bf(float f) {
    __hip_bfloat16 h = __float2bfloat16(f);
    return __builtin_bit_cast(short, h);
}

__device__ __forceinline__ int pack_bf2(float x, float y) {
    const unsigned lo = (unsigned short)f2bf(x);
    const unsigned hi = (unsigned short)f2bf(y);
    return (int)(lo | (hi << 16));
}

// ---------------------------------------------------------------------------
// PHASE 0: accumulate only.  PHASE 1: finalize only.  PHASE 2: fused w/ grid
// sync (cooperative).  All per-thread arrays statically indexed, no pointer
// aliasing (scratch-spill avoidance, cf. R11 WRITE_SIZE anomaly).
// ---------------------------------------------------------------------------
template<int PHASE>
__global__ __launch_bounds__(TPB, 4) void k_fused(const float* __restrict__ feat,
                                                  const int* __restrict__ gt,
                                                  float* __restrict__ ws,
                                                  float* __restrict__ out) {
    __shared__ int   s_lab[CHUNK];         // 8 KB
    __shared__ short s_feat[N_ * RS];      // 16.6 KB bf16 subtile (512 px)
    __shared__ float s_fin[4][256];        // 4 KB
    __shared__ float s_red[4][C_];
    __shared__ float s_cen[C_][N_ + 1];
    __shared__ float s_w[C_];
    __shared__ float s_cntv[B_ * C_];
    __shared__ float red[TPB];
    __shared__ float wsum[TPB / 64];

    const int tid  = threadIdx.x;
    const int lane = tid & 63, wid = tid >> 6;
    const int b     = blockIdx.x / BPI;
    const int chunk = blockIdx.x % BPI;
    const int base  = chunk * CHUNK;

    const int*   __restrict__ gb = gt   + (size_t)b * P_ + base;
    const float* __restrict__ fb = feat + (size_t)b * N_ * P_ + base;

    if (PHASE != 1) {
        // ================= Phase A: sums + counts =================
        if (blockIdx.x == 0 && tid == 0) out[0] = 0.f;

        const int4 la = ((const int4*)gb)[tid];
        const int4 lc = ((const int4*)gb)[256 + tid];
        ((int4*)s_lab)[tid]       = la;
        ((int4*)s_lab)[256 + tid] = lc;

        float cnt[C_];
        #pragma unroll
        for (int c = 0; c < C_; ++c) {
            cnt[c] = ((la.x == c+1) ? 1.f : 0.f) + ((la.y == c+1) ? 1.f : 0.f)
                   + ((la.z == c+1) ? 1.f : 0.f) + ((la.w == c+1) ? 1.f : 0.f)
                   + ((lc.x == c+1) ? 1.f : 0.f) + ((lc.y == c+1) ? 1.f : 0.f)
                   + ((lc.z == c+1) ? 1.f : 0.f) + ((lc.w == c+1) ? 1.f : 0.f);
        }
        #pragma unroll
        for (int off = 32; off > 0; off >>= 1) {
            #pragma unroll
            for (int c = 0; c < C_; ++c) cnt[c] += __shfl_xor(cnt[c], off, 64);
        }
        if (lane == 0) {
            #pragma unroll
            for (int c = 0; c < C_; ++c) s_red[wid][c] = cnt[c];
        }

        // prefetch subtile 0 (8 coalesced dwordx4 in flight across the barrier)
        const int h   = tid >> 7;          // channel parity
        const int p4  = tid & 127;         // px4 slot within subtile
        float4 tr[8];
        #pragma unroll
        for (int j = 0; j < 8; ++j)
            tr[j] = *(const float4*)(fb + (size_t)(j * 2 + h) * P_ + p4 * 4);

        __syncthreads();   // s_lab + s_red visible
        if (tid < C_) {
            const float t = s_red[0][tid] + s_red[1][tid] + s_red[2][tid] + s_red[3][tid];
            atomicAdd(&ws[OFF_CNT + b * C_ + tid], t);
        }

        const int n   = lane & 15;          // class-1 (A row) / channel (B col)
        const int cls = n + 1;
        const int ko  = (lane >> 4) * 8;    // k-octet within 32-px chunk

        f32x4 acc = {0.f, 0.f, 0.f, 0.f};

        #pragma unroll
        for (int s = 0; s < 4; ++s) {
            if (s > 0) __syncthreads();     // all waves done reading s_feat[s-1]
            #pragma unroll
            for (int j = 0; j < 8; ++j) {
                int2 w;
                w.x = pack_bf2(tr[j].x, tr[j].y);
                w.y = pack_bf2(tr[j].z, tr[j].w);
                *(int2*)(s_feat + (j * 2 + h) * RS + p4 * 4) = w;
            }
            __syncthreads();                // subtile s staged
            if (s < 3) {                    // prefetch s+1 during MFMA
                #pragma unroll
                for (int j = 0; j < 8; ++j)
                    tr[j] = *(const float4*)(fb + (size_t)(j * 2 + h) * P_
                                             + (s + 1) * SUB + p4 * 4);
            }
            #pragma unroll
            for (int k = 0; k < 4; ++k) {
                const int t = wid * 4 + k;
                const int* lp = s_lab + s * SUB + t * 32 + ko;
                const int4 L0 = *(const int4*)(lp);
                const int4 L1 = *(const int4*)(lp + 4);
                FragU au, bu;
                au.i.x = ((L0.x == cls) ? 0x3F80 : 0) | ((L0.y == cls) ? 0x3F800000 : 0);
                au.i.y = ((L0.z == cls) ? 0x3F80 : 0) | ((L0.w == cls) ? 0x3F800000 : 0);
                au.i.z = ((L1.x == cls) ? 0x3F80 : 0) | ((L1.y == cls) ? 0x3F800000 : 0);
                au.i.w = ((L1.z == cls) ? 0x3F80 : 0) | ((L1.w == cls) ? 0x3F800000 : 0);
                bu.v = *(const bf16x8*)(s_feat + n * RS + t * 32 + ko);
                acc = __builtin_amdgcn_mfma_f32_16x16x32_bf16(au.v, bu.v, acc, 0, 0, 0);
            }
        }

        __syncthreads();
        #pragma unroll
        for (int r = 0; r < 4; ++r) s_fin[wid][lane * 4 + r] = acc[r];
        __syncthreads();
        {
            const float sv = s_fin[0][tid] + s_fin[1][tid] + s_fin[2][tid] + s_fin[3][tid];
            const int elane = tid >> 2, r = tid & 3;
            const int row = (elane >> 4) * 4 + r;   // class (D row)
            const int col = elane & 15;             // channel (D col)
            if (row < C_)
                atomicAdd(&ws[OFF_SUMS + ((size_t)b * C_ + row) * N_ + col], sv);
        }
    }

    if constexpr (PHASE == 2) {
        cg::this_grid().sync();
    }

    if (PHASE != 0) {
        // ================= Phase B: centers, push, pull =================
        if (tid < B_ * C_) s_cntv[tid] = ws[OFF_CNT + tid];
        __syncthreads();

        float n_inst = 0.f;
        #pragma unroll 8
        for (int i = 0; i < B_ * C_; ++i) n_inst += (s_cntv[i] > 0.f) ? 1.f : 0.f;

        if (tid < C_ * N_) {
            const int c = tid >> 4, nn = tid & 15;
            const float ct = s_cntv[b * C_ + c];
            s_cen[c][nn] = ws[OFF_SUMS + ((size_t)b * C_ + c) * N_ + nn] / fmaxf(ct, 1.f);
        }
        if (tid < C_) {
            const float ct = s_cntv[b * C_ + tid];
            s_w[tid] = (ct > 0.f && n_inst > 0.f) ? 1.0f / (ct * n_inst) : 0.f;
        }
        __syncthreads();

        if (chunk == 0) {
            float ps = 0.f;
            if (tid < C_ * C_) {
                const int i = tid / C_, j = tid % C_;
                if (i != j && s_cntv[b * C_ + i] > 0.f && s_cntv[b * C_ + j] > 0.f) {
                    float sq = 0.f;
                    #pragma unroll
                    for (int nn = 0; nn < N_; ++nn) {
                        const float d = s_cen[i][nn] - s_cen[j][nn];
                        sq += d * d;
                    }
                    ps = fmaxf(2.f * MARGIN_DIST_ - sqrtf(sq), 0.f);
                }
            }
            red[tid] = ps;
            __syncthreads();
            for (int s = TPB / 2; s > 0; s >>= 1) {
                if (tid < s) red[tid] += red[tid + s];
                __syncthreads();
            }
            if (tid == 0) {
                float np = 0.f;
                for (int bb_ = 0; bb_ < B_; ++bb_) {
                    int k = 0;
                    for (int c = 0; c < C_; ++c) k += (s_cntv[bb_ * C_ + c] > 0.f) ? 1 : 0;
                    np += (float)(k * (k - 1));
                }
                if (np > 0.f) atomicAdd(out, red[0] / np);   // DIST_WEIGHT = 1
            }
        }

        // ---- pull: two halves of 1024 px; direct static arrays, no lambda ----
        float acc2 = 0.f;
        #pragma unroll
        for (int hh = 0; hh < 2; ++hh) {
            const int4 lb = ((const int4*)gb)[hh * 256 + tid];
            const float* __restrict__ fh = fb + hh * 1024 + tid * 4;

            float4 v[16];
            #pragma unroll
            for (int nn = 0; nn < 16; ++nn)
                v[nn] = *(const float4*)(fh + (size_t)nn * P_);

            const bool vx = (lb.x >= 1 && lb.x <= C_);
            const bool vy = (lb.y >= 1 && lb.y <= C_);
            const bool vz = (lb.z >= 1 && lb.z <= C_);
            const bool vw = (lb.w >= 1 && lb.w <= C_);
            const int cx = vx ? lb.x - 1 : 0;
            const int cy = vy ? lb.y - 1 : 0;
            const int cz = vz ? lb.z - 1 : 0;
            const int cw = vw ? lb.w - 1 : 0;

            float sq0 = 0.f, sq1 = 0.f, sq2 = 0.f, sq3 = 0.f;
            #pragma unroll
            for (int nn = 0; nn < 16; ++nn) {
                const float d0 = v[nn].x - s_cen[cx][nn];
                const float d1 = v[nn].y - s_cen[cy][nn];
                const float d2 = v[nn].z - s_cen[cz][nn];
                const float d3 = v[nn].w - s_cen[cw][nn];
                sq0 += d0 * d0; sq1 += d1 * d1; sq2 += d2 * d2; sq3 += d3 * d3;
            }
            acc2 += fmaxf(sqrtf(sq0) - MARGIN_VAR_, 0.f) * (vx ? s_w[cx] : 0.f);
            acc2 += fmaxf(sqrtf(sq1) - MARGIN_VAR_, 0.f) * (vy ? s_w[cy] : 0.f);
            acc2 += fmaxf(sqrtf(sq2) - MARGIN_VAR_, 0.f) * (vz ? s_w[cz] : 0.f);
            acc2 += fmaxf(sqrtf(sq3) - MARGIN_VAR_, 0.f) * (vw ? s_w[cw] : 0.f);
        }

        #pragma unroll
        for (int off = 32; off > 0; off >>= 1) acc2 += __shfl_down(acc2, off, 64);
        if (lane == 0) wsum[wid] = acc2;
        __syncthreads();
        if (tid == 0) {
            float t = 0.f;
            #pragma unroll
            for (int w = 0; w < TPB / 64; ++w) t += wsum[w];
            atomicAdd(out, t);   // VAR_WEIGHT = 1
        }
    }
}

// ---------------------------------------------------------------------------
extern "C" void kernel_launch(void* const* d_in, const int* in_sizes, int n_in,
                              void* d_out, int out_size, void* d_ws, size_t ws_size,
                              hipStream_t stream) {
    const float* feat = (const float*)d_in[0];
    const int*   gt   = (const int*)d_in[1];
    float* out = (float*)d_out;
    float* ws  = (float*)d_ws;

    (void)hipMemsetAsync(d_ws, 0, WS_FLOATS * sizeof(float), stream);

    void* args[] = { (void*)&feat, (void*)&gt, (void*)&ws, (void*)&out };
    hipError_t e = hipLaunchCooperativeKernel((void*)(&k_fused<2>), dim3(NB),
                                              dim3(TPB), args, 0, stream);
    if (e != hipSuccess) {
        // Fallback: same kernel, two ordinary launches (phase-split).
        k_fused<0><<<dim3(NB), dim3(TPB), 0, stream>>>(feat, gt, ws, out);
        k_fused<1><<<dim3(NB), dim3(TPB), 0, stream>>>(feat, gt, ws, out);
    }
}

// Round 13
// 80.379 us; speedup vs baseline: 2.9081x; 2.8455x over previous
//
#include <hip/hip_runtime.h>
#include <hip/hip_bf16.h>

// Problem constants (fixed by reference setup_inputs)
constexpr int B_ = 8;
constexpr int N_ = 16;
constexpr int H_ = 368;
constexpr int W_ = 640;
constexpr int P_ = H_ * W_;          // 235520 pixels per image
constexpr int C_ = 12;               // instance ids 1..12
constexpr float MARGIN_VAR_ = 0.5f;
constexpr float MARGIN_DIST_ = 3.0f;

// Workspace layout (floats): sums + counts
constexpr int OFF_SUMS = 0;                      // [B][C][N] feature sums
constexpr int OFF_CNT  = OFF_SUMS + B_*C_*N_;    // [B][C]    pixel counts
constexpr int WS_FLOATS = OFF_CNT + B_*C_;       // 1632 floats

constexpr int TPB = 256;

constexpr int ACH  = 512;              // k_accum pixels per block
constexpr int ABPI = P_ / ACH;         // 460 (exact)
constexpr int PCHUNK = 1024;           // k_pull pixels per block
constexpr int PBPI   = P_ / PCHUNK;    // 230 (exact)
constexpr int NBLK   = B_ * PBPI;      // 1840

constexpr int RS = 520;                // LDS row stride in shorts (512 + 8 pad)

typedef short bf16x8 __attribute__((ext_vector_type(8)));   // 8 bf16 (4 VGPR)
typedef float f32x4  __attribute__((ext_vector_type(4)));   // MFMA accumulator

union FragU { int4 i; bf16x8 v; };

__device__ __forceinline__ short f2bf(float f) {
    __hip_bfloat16 h = __float2bfloat16(f);
    return __builtin_bit_cast(short, h);
}

__device__ __forceinline__ int pack_bf2(float x, float y) {
    const unsigned lo = (unsigned short)f2bf(x);
    const unsigned hi = (unsigned short)f2bf(y);
    return (int)(lo | (hi << 16));
}

// ---------------------------------------------------------------------------
// Kernel 1: per-class sums + counts via MFMA. 512 px/block, grid 3680.
// All 9 global loads (1 label int2 + 8 feat float4) issue in one burst at
// entry -> max MLP; single staging barrier; 4 MFMA per wave; small tail.
// ---------------------------------------------------------------------------
__global__ __launch_bounds__(TPB) void k_accum(const float* __restrict__ feat,
                                               const int* __restrict__ gt,
                                               float* __restrict__ ws,
                                               float* __restrict__ out) {
    __shared__ int   s_lab[ACH];           // 2 KB
    __shared__ short s_feat[N_ * RS];      // 16.6 KB bf16 tile (512 px)
    __shared__ float s_red[4][C_];
    __shared__ float s_fin[4][256];        // 4 KB

    const int tid  = threadIdx.x;
    const int lane = tid & 63, wid = tid >> 6;
    const int b     = blockIdx.x / ABPI;
    const int chunk = blockIdx.x % ABPI;
    const int base  = chunk * ACH;

    if (blockIdx.x == 0 && tid == 0) out[0] = 0.f;   // init output before k_pull

    const int*   __restrict__ gb = gt   + (size_t)b * P_ + base;
    const float* __restrict__ fb = feat + (size_t)b * N_ * P_ + base;

    // ---- one burst: labels + 8 coalesced feat float4 ----
    const int2 la = ((const int2*)gb)[tid];
    const int  h  = tid >> 7;              // channel parity
    const int  p4 = tid & 127;             // px4 slot (128 x 4 = 512 px)
    float4 tr[8];
    #pragma unroll
    for (int j = 0; j < 8; ++j)
        tr[j] = *(const float4*)(fb + (size_t)(j * 2 + h) * P_ + p4 * 4);

    ((int2*)s_lab)[tid] = la;

    // ---- per-class counts (VALU, overlaps loads) ----
    float cnt[C_];
    #pragma unroll
    for (int c = 0; c < C_; ++c)
        cnt[c] = ((la.x == c+1) ? 1.f : 0.f) + ((la.y == c+1) ? 1.f : 0.f);
    #pragma unroll
    for (int off = 32; off > 0; off >>= 1) {
        #pragma unroll
        for (int c = 0; c < C_; ++c) cnt[c] += __shfl_xor(cnt[c], off, 64);
    }
    if (lane == 0) {
        #pragma unroll
        for (int c = 0; c < C_; ++c) s_red[wid][c] = cnt[c];
    }

    // ---- stage feat -> bf16 LDS (waits on loads here) ----
    #pragma unroll
    for (int j = 0; j < 8; ++j) {
        int2 w;
        w.x = pack_bf2(tr[j].x, tr[j].y);
        w.y = pack_bf2(tr[j].z, tr[j].w);
        *(int2*)(s_feat + (j * 2 + h) * RS + p4 * 4) = w;
    }
    __syncthreads();   // s_lab + s_feat + s_red ready

    if (tid < C_) {
        const float t = s_red[0][tid] + s_red[1][tid] + s_red[2][tid] + s_red[3][tid];
        atomicAdd(&ws[OFF_CNT + b * C_ + tid], t);
    }

    // ---- MFMA: 16 k-chunks of 32 px, 4 per wave ----
    const int n   = lane & 15;              // class-1 (A row) / channel (B col)
    const int cls = n + 1;
    const int ko  = (lane >> 4) * 8;        // k-octet within 32-px chunk

    f32x4 acc = {0.f, 0.f, 0.f, 0.f};
    #pragma unroll
    for (int k = 0; k < 4; ++k) {
        const int t = wid * 4 + k;
        const int* lp = s_lab + t * 32 + ko;
        const int4 L0 = *(const int4*)(lp);
        const int4 L1 = *(const int4*)(lp + 4);
        FragU au, bu;
        au.i.x = ((L0.x == cls) ? 0x3F80 : 0) | ((L0.y == cls) ? 0x3F800000 : 0);
        au.i.y = ((L0.z == cls) ? 0x3F80 : 0) | ((L0.w == cls) ? 0x3F800000 : 0);
        au.i.z = ((L1.x == cls) ? 0x3F80 : 0) | ((L1.y == cls) ? 0x3F800000 : 0);
        au.i.w = ((L1.z == cls) ? 0x3F80 : 0) | ((L1.w == cls) ? 0x3F800000 : 0);
        bu.v = *(const bf16x8*)(s_feat + n * RS + t * 32 + ko);
        acc = __builtin_amdgcn_mfma_f32_16x16x32_bf16(au.v, bu.v, acc, 0, 0, 0);
    }

    // ---- cross-wave reduce of D, one atomic per (class,channel) ----
    #pragma unroll
    for (int r = 0; r < 4; ++r) s_fin[wid][lane * 4 + r] = acc[r];
    __syncthreads();
    {
        const float sv = s_fin[0][tid] + s_fin[1][tid] + s_fin[2][tid] + s_fin[3][tid];
        const int elane = tid >> 2, r = tid & 3;
        const int row = (elane >> 4) * 4 + r;   // class (D row)
        const int col = elane & 15;             // channel (D col)
        if (row < C_)
            atomicAdd(&ws[OFF_SUMS + ((size_t)b * C_ + row) * N_ + col], sv);
    }
}

// ---------------------------------------------------------------------------
// Kernel 2: pull loss + push loss (verbatim R9 structure, proven 26 us).
// ---------------------------------------------------------------------------
__global__ __launch_bounds__(TPB) void k_pull(const float* __restrict__ feat,
                                              const int* __restrict__ gt,
                                              const float* __restrict__ ws,
                                              float* __restrict__ out) {
    __shared__ float s_cen[C_][N_ + 1];
    __shared__ float s_w[C_];
    __shared__ float s_cntv[B_ * C_];
    __shared__ float red[TPB];
    __shared__ float wsum[TPB / 64];

    const int tid = threadIdx.x;
    // reverse round order, keep blockIdx%8 (same-XCD) alignment
    const int g2    = (NBLK / 8 - 1 - (int)(blockIdx.x >> 3)) * 8 + (blockIdx.x & 7);
    const int b     = g2 / PBPI;
    const int chunk = g2 % PBPI;
    const int base  = chunk * PCHUNK;

    const float* __restrict__ fbase = feat + (size_t)b * N_ * P_ + base + tid * 4;

    // ---- issue first 8 channel loads + labels (fly during preamble) ----
    const int4 lb = *(const int4*)(gt + (size_t)b * P_ + base + tid * 4);
    float4 va[4], vb[4];
    #pragma unroll
    for (int j = 0; j < 4; ++j) va[j] = *(const float4*)(fbase + (size_t)(j) * P_);
    #pragma unroll
    for (int j = 0; j < 4; ++j) vb[j] = *(const float4*)(fbase + (size_t)(4 + j) * P_);

    // ---- preamble: counts -> n_inst, centers, weights ----
    if (tid < B_ * C_) s_cntv[tid] = ws[OFF_CNT + tid];
    __syncthreads();

    float n_inst = 0.f;
    #pragma unroll 8
    for (int i = 0; i < B_ * C_; ++i) n_inst += (s_cntv[i] > 0.f) ? 1.f : 0.f;

    if (tid < C_ * N_) {
        const int c = tid >> 4, n = tid & 15;
        const float ct = s_cntv[b * C_ + c];
        s_cen[c][n] = ws[OFF_SUMS + ((size_t)b * C_ + c) * N_ + n] / fmaxf(ct, 1.f);
    }
    if (tid < C_) {
        const float ct = s_cntv[b * C_ + tid];
        s_w[tid] = (ct > 0.f && n_inst > 0.f) ? 1.0f / (ct * n_inst) : 0.f;
    }
    __syncthreads();

    // ---- push loss: only the chunk==0 block of each image ----
    if (chunk == 0) {
        float ps = 0.f;
        if (tid < C_ * C_) {
            const int i = tid / C_, j = tid % C_;
            if (i != j && s_cntv[b * C_ + i] > 0.f && s_cntv[b * C_ + j] > 0.f) {
                float sq = 0.f;
                #pragma unroll
                for (int n = 0; n < N_; ++n) {
                    const float d = s_cen[i][n] - s_cen[j][n];
                    sq += d * d;
                }
                ps = fmaxf(2.f * MARGIN_DIST_ - sqrtf(sq), 0.f);
            }
        }
        red[tid] = ps;
        __syncthreads();
        for (int s = TPB / 2; s > 0; s >>= 1) {
            if (tid < s) red[tid] += red[tid + s];
            __syncthreads();
        }
        if (tid == 0) {
            float np = 0.f;
            for (int bb_ = 0; bb_ < B_; ++bb_) {
                int k = 0;
                for (int c = 0; c < C_; ++c) k += (s_cntv[bb_ * C_ + c] > 0.f) ? 1 : 0;
                np += (float)(k * (k - 1));
            }
            if (np > 0.f) atomicAdd(out, red[0] / np);   // DIST_WEIGHT = 1
        }
    }

    // ---- pull main: 4 pixels/thread, channel groups pipelined ----
    const bool vx = (lb.x >= 1 && lb.x <= C_);
    const bool vy = (lb.y >= 1 && lb.y <= C_);
    const bool vz = (lb.z >= 1 && lb.z <= C_);
    const bool vw = (lb.w >= 1 && lb.w <= C_);
    const int cx = vx ? lb.x - 1 : 0;
    const int cy = vy ? lb.y - 1 : 0;
    const int cz = vz ? lb.z - 1 : 0;
    const int cw = vw ? lb.w - 1 : 0;

    float sq0 = 0.f, sq1 = 0.f, sq2 = 0.f, sq3 = 0.f;

    auto consume4 = [&](const float4* r, int cb) {
        #pragma unroll
        for (int j = 0; j < 4; ++j) {
            const int nn = cb + j;
            const float d0 = r[j].x - s_cen[cx][nn];
            const float d1 = r[j].y - s_cen[cy][nn];
            const float d2 = r[j].z - s_cen[cz][nn];
            const float d3 = r[j].w - s_cen[cw][nn];
            sq0 += d0 * d0; sq1 += d1 * d1; sq2 += d2 * d2; sq3 += d3 * d3;
        }
    };

    consume4(va, 0);
    #pragma unroll
    for (int j = 0; j < 4; ++j) va[j] = *(const float4*)(fbase + (size_t)(8 + j) * P_);
    consume4(vb, 4);
    #pragma unroll
    for (int j = 0; j < 4; ++j) vb[j] = *(const float4*)(fbase + (size_t)(12 + j) * P_);
    consume4(va, 8);
    consume4(vb, 12);

    float acc = 0.f;
    acc += fmaxf(sqrtf(sq0) - MARGIN_VAR_, 0.f) * (vx ? s_w[cx] : 0.f);
    acc += fmaxf(sqrtf(sq1) - MARGIN_VAR_, 0.f) * (vy ? s_w[cy] : 0.f);
    acc += fmaxf(sqrtf(sq2) - MARGIN_VAR_, 0.f) * (vz ? s_w[cz] : 0.f);
    acc += fmaxf(sqrtf(sq3) - MARGIN_VAR_, 0.f) * (vw ? s_w[cw] : 0.f);

    #pragma unroll
    for (int off = 32; off > 0; off >>= 1) acc += __shfl_down(acc, off, 64);
    const int lane = tid & 63, wid = tid >> 6;
    if (lane == 0) wsum[wid] = acc;
    __syncthreads();
    if (tid == 0) {
        float t = 0.f;
        #pragma unroll
        for (int w = 0; w < TPB / 64; ++w) t += wsum[w];
        atomicAdd(out, t);   // VAR_WEIGHT = 1
    }
}

// ---------------------------------------------------------------------------
extern "C" void kernel_launch(void* const* d_in, const int* in_sizes, int n_in,
                              void* d_out, int out_size, void* d_ws, size_t ws_size,
                              hipStream_t stream) {
    const float* feat = (const float*)d_in[0];
    const int*   gt   = (const int*)d_in[1];
    float* out = (float*)d_out;
    float* ws  = (float*)d_ws;

    (void)hipMemsetAsync(d_ws, 0, WS_FLOATS * sizeof(float), stream);

    k_accum<<<dim3(B_ * ABPI), dim3(TPB), 0, stream>>>(feat, gt, ws, out);
    k_pull <<<dim3(NBLK), dim3(TPB), 0, stream>>>(feat, gt, ws, out);
}

// Round 14
// 64.969 us; speedup vs baseline: 3.5979x; 1.2372x over previous
//
#include <hip/hip_runtime.h>
#include <hip/hip_bf16.h>

// Problem constants (fixed by reference setup_inputs)
constexpr int B_ = 8;
constexpr int N_ = 16;
constexpr int H_ = 368;
constexpr int W_ = 640;
constexpr int P_ = H_ * W_;          // 235520 pixels per image
constexpr int C_ = 12;               // instance ids 1..12
constexpr float MARGIN_VAR_ = 0.5f;
constexpr float MARGIN_DIST_ = 3.0f;

// Workspace layout (floats): sums + counts
constexpr int OFF_SUMS = 0;                      // [B][C][N] feature sums
constexpr int OFF_CNT  = OFF_SUMS + B_*C_*N_;    // [B][C]    pixel counts
constexpr int WS_FLOATS = OFF_CNT + B_*C_;       // 1632 floats

constexpr int TPB = 256;

constexpr int ACH   = 1024;            // k_accum pixels per chunk
constexpr int APAIR = 2 * ACH;         // 2048 px per block (2 chunks)
constexpr int ABPI  = P_ / APAIR;      // 115 (exact) block-pairs per image
constexpr int PCHUNK = 1024;           // k_pull pixels per block
constexpr int PBPI   = P_ / PCHUNK;    // 230 (exact)
constexpr int NBLK   = B_ * PBPI;      // 1840

constexpr int RS = 1048;               // LDS row stride in shorts (1024 + 24 pad)

typedef short bf16x8 __attribute__((ext_vector_type(8)));   // 8 bf16 (4 VGPR)
typedef float f32x4  __attribute__((ext_vector_type(4)));   // MFMA accumulator

union FragU { int4 i; bf16x8 v; };

__device__ __forceinline__ short f2bf(float f) {
    __hip_bfloat16 h = __float2bfloat16(f);
    return __builtin_bit_cast(short, h);
}

__device__ __forceinline__ int pack_bf2(float x, float y) {
    const unsigned lo = (unsigned short)f2bf(x);
    const unsigned hi = (unsigned short)f2bf(y);
    return (int)(lo | (hi << 16));
}

// ---------------------------------------------------------------------------
// Kernel 1: per-class sums + counts via MFMA. Two 1024-px chunks per block:
// chunk-1 loads are issued as chunk-0 registers retire, flying across
// chunk-0's MFMA; acc accumulates across chunks; reduce/atomic tail once.
// ---------------------------------------------------------------------------
__global__ __launch_bounds__(TPB) void k_accum(const float* __restrict__ feat,
                                               const int* __restrict__ gt,
                                               float* __restrict__ ws,
                                               float* __restrict__ out) {
    __shared__ int   s_lab[2][ACH];        // 8 KB (s_lab[0] reused as s_fin)
    __shared__ short s_feat[N_ * RS];      // 32.8 KB bf16 tile (1024 px)
    __shared__ float s_red[4][C_];

    const int tid  = threadIdx.x;
    const int lane = tid & 63, wid = tid >> 6;
    const int b    = blockIdx.x / ABPI;
    const int pair = blockIdx.x % ABPI;
    const int base = pair * APAIR;

    if (blockIdx.x == 0 && tid == 0) out[0] = 0.f;   // init output before k_pull

    const int*   __restrict__ gb = gt   + (size_t)b * P_ + base;
    const float* __restrict__ fb = feat + (size_t)b * N_ * P_ + base;

    // ---- entry burst: labels (both chunks) + 16 feat float4 (chunk 0) ----
    const int4 lab0 = ((const int4*)gb)[tid];
    const int4 lab1 = ((const int4*)gb)[256 + tid];
    float4 tr[16];
    #pragma unroll
    for (int j = 0; j < 16; ++j)
        tr[j] = *(const float4*)(fb + (size_t)j * P_ + tid * 4);

    ((int4*)&s_lab[0][0])[tid] = lab0;
    ((int4*)&s_lab[1][0])[tid] = lab1;

    // ---- per-class counts over both chunks (overlaps loads) ----
    float cnt[C_];
    #pragma unroll
    for (int c = 0; c < C_; ++c) {
        cnt[c] = ((lab0.x == c+1) ? 1.f : 0.f) + ((lab0.y == c+1) ? 1.f : 0.f)
               + ((lab0.z == c+1) ? 1.f : 0.f) + ((lab0.w == c+1) ? 1.f : 0.f)
               + ((lab1.x == c+1) ? 1.f : 0.f) + ((lab1.y == c+1) ? 1.f : 0.f)
               + ((lab1.z == c+1) ? 1.f : 0.f) + ((lab1.w == c+1) ? 1.f : 0.f);
    }
    #pragma unroll
    for (int off = 32; off > 0; off >>= 1) {
        #pragma unroll
        for (int c = 0; c < C_; ++c) cnt[c] += __shfl_xor(cnt[c], off, 64);
    }
    if (lane == 0) {
        #pragma unroll
        for (int c = 0; c < C_; ++c) s_red[wid][c] = cnt[c];
    }

    // ---- convert chunk 0 -> LDS; reissue each reg with chunk-1 load ----
    #pragma unroll
    for (int j = 0; j < 16; ++j) {
        const float4 v = tr[j];
        tr[j] = *(const float4*)(fb + (size_t)j * P_ + ACH + tid * 4);  // chunk 1
        int2 w; w.x = pack_bf2(v.x, v.y); w.y = pack_bf2(v.z, v.w);
        *(int2*)(s_feat + j * RS + tid * 4) = w;
    }
    __syncthreads();   // s_lab + s_feat(c0) + s_red ready

    if (tid < C_) {
        const float t = s_red[0][tid] + s_red[1][tid] + s_red[2][tid] + s_red[3][tid];
        atomicAdd(&ws[OFF_CNT + b * C_ + tid], t);
    }

    const int n   = lane & 15;              // class-1 (A row) / channel (B col)
    const int cls = n + 1;
    const int ko  = (lane >> 4) * 8;        // k-octet within 32-px chunk

    f32x4 acc = {0.f, 0.f, 0.f, 0.f};

    // ---- MFMA chunk 0 (chunk-1 loads in flight underneath) ----
    #pragma unroll
    for (int k = 0; k < 8; ++k) {
        const int t = wid * 8 + k;
        const int* lp = &s_lab[0][0] + t * 32 + ko;
        const int4 L0 = *(const int4*)(lp);
        const int4 L1 = *(const int4*)(lp + 4);
        FragU au, bu;
        au.i.x = ((L0.x == cls) ? 0x3F80 : 0) | ((L0.y == cls) ? 0x3F800000 : 0);
        au.i.y = ((L0.z == cls) ? 0x3F80 : 0) | ((L0.w == cls) ? 0x3F800000 : 0);
        au.i.z = ((L1.x == cls) ? 0x3F80 : 0) | ((L1.y == cls) ? 0x3F800000 : 0);
        au.i.w = ((L1.z == cls) ? 0x3F80 : 0) | ((L1.w == cls) ? 0x3F800000 : 0);
        bu.v = *(const bf16x8*)(s_feat + n * RS + t * 32 + ko);
        acc = __builtin_amdgcn_mfma_f32_16x16x32_bf16(au.v, bu.v, acc, 0, 0, 0);
    }
    __syncthreads();   // all waves done reading s_feat(c0)

    // ---- convert chunk 1 -> LDS (loads mostly arrived during MFMA) ----
    #pragma unroll
    for (int j = 0; j < 16; ++j) {
        int2 w; w.x = pack_bf2(tr[j].x, tr[j].y); w.y = pack_bf2(tr[j].z, tr[j].w);
        *(int2*)(s_feat + j * RS + tid * 4) = w;
    }
    __syncthreads();   // s_feat(c1) staged; s_lab[0] now dead

    // ---- MFMA chunk 1 ----
    #pragma unroll
    for (int k = 0; k < 8; ++k) {
        const int t = wid * 8 + k;
        const int* lp = &s_lab[1][0] + t * 32 + ko;
        const int4 L0 = *(const int4*)(lp);
        const int4 L1 = *(const int4*)(lp + 4);
        FragU au, bu;
        au.i.x = ((L0.x == cls) ? 0x3F80 : 0) | ((L0.y == cls) ? 0x3F800000 : 0);
        au.i.y = ((L0.z == cls) ? 0x3F80 : 0) | ((L0.w == cls) ? 0x3F800000 : 0);
        au.i.z = ((L1.x == cls) ? 0x3F80 : 0) | ((L1.y == cls) ? 0x3F800000 : 0);
        au.i.w = ((L1.z == cls) ? 0x3F80 : 0) | ((L1.w == cls) ? 0x3F800000 : 0);
        bu.v = *(const bf16x8*)(s_feat + n * RS + t * 32 + ko);
        acc = __builtin_amdgcn_mfma_f32_16x16x32_bf16(au.v, bu.v, acc, 0, 0, 0);
    }

    // ---- single tail: s_fin overlays dead s_lab[0] (disjoint from s_lab[1]) ----
    float* s_fin = (float*)&s_lab[0][0];   // 4 KB
    #pragma unroll
    for (int r = 0; r < 4; ++r) s_fin[wid * 256 + lane * 4 + r] = acc[r];
    __syncthreads();
    {
        const float sv = s_fin[0 * 256 + tid] + s_fin[1 * 256 + tid]
                       + s_fin[2 * 256 + tid] + s_fin[3 * 256 + tid];
        const int elane = tid >> 2, r = tid & 3;
        const int row = (elane >> 4) * 4 + r;   // class (D row)
        const int col = elane & 15;             // channel (D col)
        if (row < C_)
            atomicAdd(&ws[OFF_SUMS + ((size_t)b * C_ + row) * N_ + col], sv);
    }
}

// ---------------------------------------------------------------------------
// Kernel 2: pull loss + push loss (verbatim R9 structure).
// ---------------------------------------------------------------------------
__global__ __launch_bounds__(TPB) void k_pull(const float* __restrict__ feat,
                                              const int* __restrict__ gt,
                                              const float* __restrict__ ws,
                                              float* __restrict__ out) {
    __shared__ float s_cen[C_][N_ + 1];
    __shared__ float s_w[C_];
    __shared__ float s_cntv[B_ * C_];
    __shared__ float red[TPB];
    __shared__ float wsum[TPB / 64];

    const int tid = threadIdx.x;
    // reverse round order, keep blockIdx%8 (same-XCD) alignment
    const int g2    = (NBLK / 8 - 1 - (int)(blockIdx.x >> 3)) * 8 + (blockIdx.x & 7);
    const int b     = g2 / PBPI;
    const int chunk = g2 % PBPI;
    const int base  = chunk * PCHUNK;

    const float* __restrict__ fbase = feat + (size_t)b * N_ * P_ + base + tid * 4;

    // ---- issue first 8 channel loads + labels (fly during preamble) ----
    const int4 lb = *(const int4*)(gt + (size_t)b * P_ + base + tid * 4);
    float4 va[4], vb[4];
    #pragma unroll
    for (int j = 0; j < 4; ++j) va[j] = *(const float4*)(fbase + (size_t)(j) * P_);
    #pragma unroll
    for (int j = 0; j < 4; ++j) vb[j] = *(const float4*)(fbase + (size_t)(4 + j) * P_);

    // ---- preamble: counts -> n_inst, centers, weights ----
    if (tid < B_ * C_) s_cntv[tid] = ws[OFF_CNT + tid];
    __syncthreads();

    float n_inst = 0.f;
    #pragma unroll 8
    for (int i = 0; i < B_ * C_; ++i) n_inst += (s_cntv[i] > 0.f) ? 1.f : 0.f;

    if (tid < C_ * N_) {
        const int c = tid >> 4, n = tid & 15;
        const float ct = s_cntv[b * C_ + c];
        s_cen[c][n] = ws[OFF_SUMS + ((size_t)b * C_ + c) * N_ + n] / fmaxf(ct, 1.f);
    }
    if (tid < C_) {
        const float ct = s_cntv[b * C_ + tid];
        s_w[tid] = (ct > 0.f && n_inst > 0.f) ? 1.0f / (ct * n_inst) : 0.f;
    }
    __syncthreads();

    // ---- push loss: only the chunk==0 block of each image ----
    if (chunk == 0) {
        float ps = 0.f;
        if (tid < C_ * C_) {
            const int i = tid / C_, j = tid % C_;
            if (i != j && s_cntv[b * C_ + i] > 0.f && s_cntv[b * C_ + j] > 0.f) {
                float sq = 0.f;
                #pragma unroll
                for (int n = 0; n < N_; ++n) {
                    const float d = s_cen[i][n] - s_cen[j][n];
                    sq += d * d;
                }
                ps = fmaxf(2.f * MARGIN_DIST_ - sqrtf(sq), 0.f);
            }
        }
        red[tid] = ps;
        __syncthreads();
        for (int s = TPB / 2; s > 0; s >>= 1) {
            if (tid < s) red[tid] += red[tid + s];
            __syncthreads();
        }
        if (tid == 0) {
            float np = 0.f;
            for (int bb_ = 0; bb_ < B_; ++bb_) {
                int k = 0;
                for (int c = 0; c < C_; ++c) k += (s_cntv[bb_ * C_ + c] > 0.f) ? 1 : 0;
                np += (float)(k * (k - 1));
            }
            if (np > 0.f) atomicAdd(out, red[0] / np);   // DIST_WEIGHT = 1
        }
    }

    // ---- pull main: 4 pixels/thread, channel groups pipelined ----
    const bool vx = (lb.x >= 1 && lb.x <= C_);
    const bool vy = (lb.y >= 1 && lb.y <= C_);
    const bool vz = (lb.z >= 1 && lb.z <= C_);
    const bool vw = (lb.w >= 1 && lb.w <= C_);
    const int cx = vx ? lb.x - 1 : 0;
    const int cy = vy ? lb.y - 1 : 0;
    const int cz = vz ? lb.z - 1 : 0;
    const int cw = vw ? lb.w - 1 : 0;

    float sq0 = 0.f, sq1 = 0.f, sq2 = 0.f, sq3 = 0.f;

    auto consume4 = [&](const float4* r, int cb) {
        #pragma unroll
        for (int j = 0; j < 4; ++j) {
            const int nn = cb + j;
            const float d0 = r[j].x - s_cen[cx][nn];
            const float d1 = r[j].y - s_cen[cy][nn];
            const float d2 = r[j].z - s_cen[cz][nn];
            const float d3 = r[j].w - s_cen[cw][nn];
            sq0 += d0 * d0; sq1 += d1 * d1; sq2 += d2 * d2; sq3 += d3 * d3;
        }
    };

    consume4(va, 0);
    #pragma unroll
    for (int j = 0; j < 4; ++j) va[j] = *(const float4*)(fbase + (size_t)(8 + j) * P_);
    consume4(vb, 4);
    #pragma unroll
    for (int j = 0; j < 4; ++j) vb[j] = *(const float4*)(fbase + (size_t)(12 + j) * P_);
    consume4(va, 8);
    consume4(vb, 12);

    float acc = 0.f;
    acc += fmaxf(sqrtf(sq0) - MARGIN_VAR_, 0.f) * (vx ? s_w[cx] : 0.f);
    acc += fmaxf(sqrtf(sq1) - MARGIN_VAR_, 0.f) * (vy ? s_w[cy] : 0.f);
    acc += fmaxf(sqrtf(sq2) - MARGIN_VAR_, 0.f) * (vz ? s_w[cz] : 0.f);
    acc += fmaxf(sqrtf(sq3) - MARGIN_VAR_, 0.f) * (vw ? s_w[cw] : 0.f);

    #pragma unroll
    for (int off = 32; off > 0; off >>= 1) acc += __shfl_down(acc, off, 64);
    const int lane = tid & 63, wid = tid >> 6;
    if (lane == 0) wsum[wid] = acc;
    __syncthreads();
    if (tid == 0) {
        float t = 0.f;
        #pragma unroll
        for (int w = 0; w < TPB / 64; ++w) t += wsum[w];
        atomicAdd(out, t);   // VAR_WEIGHT = 1
    }
}

// ---------------------------------------------------------------------------
extern "C" void kernel_launch(void* const* d_in, const int* in_sizes, int n_in,
                              void* d_out, int out_size, void* d_ws, size_t ws_size,
                              hipStream_t stream) {
    const float* feat = (const float*)d_in[0];
    const int*   gt   = (const int*)d_in[1];
    float* out = (float*)d_out;
    float* ws  = (float*)d_ws;

    (void)hipMemsetAsync(d_ws, 0, WS_FLOATS * sizeof(float), stream);

    k_accum<<<dim3(B_ * ABPI), dim3(TPB), 0, stream>>>(feat, gt, ws, out);
    k_pull <<<dim3(NBLK), dim3(TPB), 0, stream>>>(feat, gt, ws, out);
}

// Round 15
// 59.443 us; speedup vs baseline: 3.9324x; 1.0930x over previous
//
#include <hip/hip_runtime.h>
#include <hip/hip_bf16.h>

// Problem constants (fixed by reference setup_inputs)
constexpr int B_ = 8;
constexpr int N_ = 16;
constexpr int H_ = 368;
constexpr int W_ = 640;
constexpr int P_ = H_ * W_;          // 235520 pixels per image
constexpr int C_ = 12;               // instance ids 1..12
constexpr float MARGIN_VAR_ = 0.5f;
constexpr float MARGIN_DIST_ = 3.0f;

// Workspace layout (floats): sums + counts
constexpr int OFF_SUMS = 0;                      // [B][C][N] feature sums
constexpr int OFF_CNT  = OFF_SUMS + B_*C_*N_;    // [B][C]    pixel counts
constexpr int WS_FLOATS = OFF_CNT + B_*C_;       // 1632 floats

constexpr int TPB = 256;

constexpr int ACH   = 1024;            // k_accum pixels per chunk
constexpr int APAIR = 2 * ACH;         // 2048 px per block (2 chunks)
constexpr int ABPI  = P_ / APAIR;      // 115 (exact)
constexpr int PCH   = 1024;            // k_pull pixels per chunk
constexpr int PPAIR = 2 * PCH;         // 2048 px per block
constexpr int PBPI  = P_ / PPAIR;      // 115 (exact)
constexpr int PNB   = B_ * PBPI;       // 920

constexpr int RS = 1048;               // LDS row stride in shorts (1024 + 24 pad)

typedef short bf16x8 __attribute__((ext_vector_type(8)));   // 8 bf16 (4 VGPR)
typedef float f32x4  __attribute__((ext_vector_type(4)));   // MFMA accumulator

union FragU { int4 i; bf16x8 v; };

__device__ __forceinline__ short f2bf(float f) {
    __hip_bfloat16 h = __float2bfloat16(f);
    return __builtin_bit_cast(short, h);
}

__device__ __forceinline__ int pack_bf2(float x, float y) {
    const unsigned lo = (unsigned short)f2bf(x);
    const unsigned hi = (unsigned short)f2bf(y);
    return (int)(lo | (hi << 16));
}

// ---------------------------------------------------------------------------
// Kernel 1: per-class sums + counts via MFMA. Two 1024-px chunks per block;
// byte-packed labels in LDS (2 KB) -> total LDS ~39.9 KB -> 4 blocks/CU.
// ---------------------------------------------------------------------------
__global__ __launch_bounds__(TPB) void k_accum(const float* __restrict__ feat,
                                               const int* __restrict__ gt,
                                               float* __restrict__ ws,
                                               float* __restrict__ out) {
    __shared__ int   s_lab8[APAIR / 4];    // 2 KB: 4 labels per int (bytes)
    __shared__ short s_feat[N_ * RS];      // 32.8 KB bf16 tile (1024 px)
    __shared__ float s_red[4][C_];
    __shared__ float s_fin[1024];          // 4 KB

    const int tid  = threadIdx.x;
    const int lane = tid & 63, wid = tid >> 6;
    const int b    = blockIdx.x / ABPI;
    const int pair = blockIdx.x % ABPI;
    const int base = pair * APAIR;

    if (blockIdx.x == 0 && tid == 0) out[0] = 0.f;   // init output before k_pull

    const int*   __restrict__ gb = gt   + (size_t)b * P_ + base;
    const float* __restrict__ fb = feat + (size_t)b * N_ * P_ + base;

    // ---- entry burst: labels (both chunks) + 16 feat float4 (chunk 0) ----
    const int4 lab0 = ((const int4*)gb)[tid];
    const int4 lab1 = ((const int4*)gb)[256 + tid];
    float4 tr[16];
    #pragma unroll
    for (int j = 0; j < 16; ++j)
        tr[j] = *(const float4*)(fb + (size_t)j * P_ + tid * 4);

    s_lab8[tid]       = lab0.x | (lab0.y << 8) | (lab0.z << 16) | (lab0.w << 24);
    s_lab8[256 + tid] = lab1.x | (lab1.y << 8) | (lab1.z << 16) | (lab1.w << 24);

    // ---- per-class counts over both chunks (overlaps loads) ----
    float cnt[C_];
    #pragma unroll
    for (int c = 0; c < C_; ++c) {
        cnt[c] = ((lab0.x == c+1) ? 1.f : 0.f) + ((lab0.y == c+1) ? 1.f : 0.f)
               + ((lab0.z == c+1) ? 1.f : 0.f) + ((lab0.w == c+1) ? 1.f : 0.f)
               + ((lab1.x == c+1) ? 1.f : 0.f) + ((lab1.y == c+1) ? 1.f : 0.f)
               + ((lab1.z == c+1) ? 1.f : 0.f) + ((lab1.w == c+1) ? 1.f : 0.f);
    }
    #pragma unroll
    for (int off = 32; off > 0; off >>= 1) {
        #pragma unroll
        for (int c = 0; c < C_; ++c) cnt[c] += __shfl_xor(cnt[c], off, 64);
    }
    if (lane == 0) {
        #pragma unroll
        for (int c = 0; c < C_; ++c) s_red[wid][c] = cnt[c];
    }

    // ---- convert chunk 0 -> LDS; reissue each reg with chunk-1 load ----
    #pragma unroll
    for (int j = 0; j < 16; ++j) {
        const float4 v = tr[j];
        tr[j] = *(const float4*)(fb + (size_t)j * P_ + ACH + tid * 4);  // chunk 1
        int2 w; w.x = pack_bf2(v.x, v.y); w.y = pack_bf2(v.z, v.w);
        *(int2*)(s_feat + j * RS + tid * 4) = w;
    }
    __syncthreads();   // s_lab8 + s_feat(c0) + s_red ready

    if (tid < C_) {
        const float t = s_red[0][tid] + s_red[1][tid] + s_red[2][tid] + s_red[3][tid];
        atomicAdd(&ws[OFF_CNT + b * C_ + tid], t);
    }

    const int n   = lane & 15;              // class-1 (A row) / channel (B col)
    const unsigned cls = (unsigned)(n + 1);
    const int ko  = (lane >> 4) * 8;        // k-octet within 32-px chunk

    f32x4 acc = {0.f, 0.f, 0.f, 0.f};

    // ---- MFMA chunk 0 (chunk-1 loads in flight underneath) ----
    #pragma unroll
    for (int k = 0; k < 8; ++k) {
        const int t = wid * 8 + k;
        const int2 L = *(const int2*)(s_lab8 + t * 8 + (ko >> 2));
        const unsigned u0 = (unsigned)L.x, u1 = (unsigned)L.y;
        FragU au, bu;
        au.i.x = (((u0      ) & 0xFF) == cls ? 0x3F80 : 0) | (((u0 >>  8) & 0xFF) == cls ? 0x3F800000 : 0);
        au.i.y = (((u0 >> 16) & 0xFF) == cls ? 0x3F80 : 0) | (((u0 >> 24)       ) == cls ? 0x3F800000 : 0);
        au.i.z = (((u1      ) & 0xFF) == cls ? 0x3F80 : 0) | (((u1 >>  8) & 0xFF) == cls ? 0x3F800000 : 0);
        au.i.w = (((u1 >> 16) & 0xFF) == cls ? 0x3F80 : 0) | (((u1 >> 24)       ) == cls ? 0x3F800000 : 0);
        bu.v = *(const bf16x8*)(s_feat + n * RS + t * 32 + ko);
        acc = __builtin_amdgcn_mfma_f32_16x16x32_bf16(au.v, bu.v, acc, 0, 0, 0);
    }
    __syncthreads();   // all waves done reading s_feat(c0)

    // ---- convert chunk 1 -> LDS (loads arrived during MFMA) ----
    #pragma unroll
    for (int j = 0; j < 16; ++j) {
        int2 w; w.x = pack_bf2(tr[j].x, tr[j].y); w.y = pack_bf2(tr[j].z, tr[j].w);
        *(int2*)(s_feat + j * RS + tid * 4) = w;
    }
    __syncthreads();

    // ---- MFMA chunk 1 ----
    #pragma unroll
    for (int k = 0; k < 8; ++k) {
        const int t = wid * 8 + k;
        const int2 L = *(const int2*)(s_lab8 + 256 + t * 8 + (ko >> 2));
        const unsigned u0 = (unsigned)L.x, u1 = (unsigned)L.y;
        FragU au, bu;
        au.i.x = (((u0      ) & 0xFF) == cls ? 0x3F80 : 0) | (((u0 >>  8) & 0xFF) == cls ? 0x3F800000 : 0);
        au.i.y = (((u0 >> 16) & 0xFF) == cls ? 0x3F80 : 0) | (((u0 >> 24)       ) == cls ? 0x3F800000 : 0);
        au.i.z = (((u1      ) & 0xFF) == cls ? 0x3F80 : 0) | (((u1 >>  8) & 0xFF) == cls ? 0x3F800000 : 0);
        au.i.w = (((u1 >> 16) & 0xFF) == cls ? 0x3F80 : 0) | (((u1 >> 24)       ) == cls ? 0x3F800000 : 0);
        bu.v = *(const bf16x8*)(s_feat + n * RS + t * 32 + ko);
        acc = __builtin_amdgcn_mfma_f32_16x16x32_bf16(au.v, bu.v, acc, 0, 0, 0);
    }

    // ---- single tail ----
    #pragma unroll
    for (int r = 0; r < 4; ++r) s_fin[wid * 256 + lane * 4 + r] = acc[r];
    __syncthreads();
    {
        const float sv = s_fin[0 * 256 + tid] + s_fin[1 * 256 + tid]
                       + s_fin[2 * 256 + tid] + s_fin[3 * 256 + tid];
        const int elane = tid >> 2, r = tid & 3;
        const int row = (elane >> 4) * 4 + r;   // class (D row)
        const int col = elane & 15;             // channel (D col)
        if (row < C_)
            atomicAdd(&ws[OFF_SUMS + ((size_t)b * C_ + row) * N_ + col], sv);
    }
}

// ---------------------------------------------------------------------------
// Kernel 2: pull + push. Two 1024-px chunks per block (preamble amortized,
// 8-deep rolling load buffer never drains). Reverse-order block mapping.
// ---------------------------------------------------------------------------
__global__ __launch_bounds__(TPB) void k_pull(const float* __restrict__ feat,
                                              const int* __restrict__ gt,
                                              const float* __restrict__ ws,
                                              float* __restrict__ out) {
    __shared__ float s_cen[C_][N_ + 1];
    __shared__ float s_w[C_];
    __shared__ float s_cntv[B_ * C_];
    __shared__ float red[TPB];
    __shared__ float wsum[TPB / 64];

    const int tid = threadIdx.x;
    // reverse round order, keep blockIdx%8 (same-XCD) alignment
    const int g2   = (PNB / 8 - 1 - (int)(blockIdx.x >> 3)) * 8 + (blockIdx.x & 7);
    const int b    = g2 / PBPI;
    const int pair = g2 % PBPI;
    const int base = pair * PPAIR;

    const int*   __restrict__ gb = gt + (size_t)b * P_ + base;
    const float* __restrict__ f0 = feat + (size_t)b * N_ * P_ + base + tid * 4;
    const float* __restrict__ f1 = f0 + PCH;

    // ---- issue labels + first 8 chunk-0 channel loads (fly during preamble) ----
    const int4 lb0 = ((const int4*)gb)[tid];
    const int4 lb1 = ((const int4*)gb)[256 + tid];
    float4 va[4], vb[4];
    #pragma unroll
    for (int j = 0; j < 4; ++j) va[j] = *(const float4*)(f0 + (size_t)j * P_);
    #pragma unroll
    for (int j = 0; j < 4; ++j) vb[j] = *(const float4*)(f0 + (size_t)(4 + j) * P_);

    // ---- preamble: counts -> n_inst, centers, weights ----
    if (tid < B_ * C_) s_cntv[tid] = ws[OFF_CNT + tid];
    __syncthreads();

    float n_inst = 0.f;
    #pragma unroll 8
    for (int i = 0; i < B_ * C_; ++i) n_inst += (s_cntv[i] > 0.f) ? 1.f : 0.f;

    if (tid < C_ * N_) {
        const int c = tid >> 4, n = tid & 15;
        const float ct = s_cntv[b * C_ + c];
        s_cen[c][n] = ws[OFF_SUMS + ((size_t)b * C_ + c) * N_ + n] / fmaxf(ct, 1.f);
    }
    if (tid < C_) {
        const float ct = s_cntv[b * C_ + tid];
        s_w[tid] = (ct > 0.f && n_inst > 0.f) ? 1.0f / (ct * n_inst) : 0.f;
    }
    __syncthreads();

    // ---- push loss: once per image (pair==0 block) ----
    if (pair == 0) {
        float ps = 0.f;
        if (tid < C_ * C_) {
            const int i = tid / C_, j = tid % C_;
            if (i != j && s_cntv[b * C_ + i] > 0.f && s_cntv[b * C_ + j] > 0.f) {
                float sq = 0.f;
                #pragma unroll
                for (int n = 0; n < N_; ++n) {
                    const float d = s_cen[i][n] - s_cen[j][n];
                    sq += d * d;
                }
                ps = fmaxf(2.f * MARGIN_DIST_ - sqrtf(sq), 0.f);
            }
        }
        red[tid] = ps;
        __syncthreads();
        for (int s = TPB / 2; s > 0; s >>= 1) {
            if (tid < s) red[tid] += red[tid + s];
            __syncthreads();
        }
        if (tid == 0) {
            float np = 0.f;
            for (int bb_ = 0; bb_ < B_; ++bb_) {
                int k = 0;
                for (int c = 0; c < C_; ++c) k += (s_cntv[bb_ * C_ + c] > 0.f) ? 1 : 0;
                np += (float)(k * (k - 1));
            }
            if (np > 0.f) atomicAdd(out, red[0] / np);   // DIST_WEIGHT = 1
        }
    }

    float accv = 0.f;

    // =================== chunk 0 ===================
    {
        const bool vx = (lb0.x >= 1 && lb0.x <= C_);
        const bool vy = (lb0.y >= 1 && lb0.y <= C_);
        const bool vz = (lb0.z >= 1 && lb0.z <= C_);
        const bool vw = (lb0.w >= 1 && lb0.w <= C_);
        const int cx = vx ? lb0.x - 1 : 0;
        const int cy = vy ? lb0.y - 1 : 0;
        const int cz = vz ? lb0.z - 1 : 0;
        const int cw = vw ? lb0.w - 1 : 0;

        float sq0 = 0.f, sq1 = 0.f, sq2 = 0.f, sq3 = 0.f;

        // consume va (c0 ch0-3), refill va <- c0 ch8-11
        #pragma unroll
        for (int j = 0; j < 4; ++j) {
            const float4 r = va[j];
            va[j] = *(const float4*)(f0 + (size_t)(8 + j) * P_);
            const float d0 = r.x - s_cen[cx][j],     d1 = r.y - s_cen[cy][j];
            const float d2 = r.z - s_cen[cz][j],     d3 = r.w - s_cen[cw][j];
            sq0 += d0*d0; sq1 += d1*d1; sq2 += d2*d2; sq3 += d3*d3;
        }
        // consume vb (c0 ch4-7), refill vb <- c0 ch12-15
        #pragma unroll
        for (int j = 0; j < 4; ++j) {
            const float4 r = vb[j];
            vb[j] = *(const float4*)(f0 + (size_t)(12 + j) * P_);
            const int nn = 4 + j;
            const float d0 = r.x - s_cen[cx][nn],    d1 = r.y - s_cen[cy][nn];
            const float d2 = r.z - s_cen[cz][nn],    d3 = r.w - s_cen[cw][nn];
            sq0 += d0*d0; sq1 += d1*d1; sq2 += d2*d2; sq3 += d3*d3;
        }
        // consume va (c0 ch8-11), refill va <- c1 ch0-3
        #pragma unroll
        for (int j = 0; j < 4; ++j) {
            const float4 r = va[j];
            va[j] = *(const float4*)(f1 + (size_t)j * P_);
            const int nn = 8 + j;
            const float d0 = r.x - s_cen[cx][nn],    d1 = r.y - s_cen[cy][nn];
            const float d2 = r.z - s_cen[cz][nn],    d3 = r.w - s_cen[cw][nn];
            sq0 += d0*d0; sq1 += d1*d1; sq2 += d2*d2; sq3 += d3*d3;
        }
        // consume vb (c0 ch12-15), refill vb <- c1 ch4-7
        #pragma unroll
        for (int j = 0; j < 4; ++j) {
            const float4 r = vb[j];
            vb[j] = *(const float4*)(f1 + (size_t)(4 + j) * P_);
            const int nn = 12 + j;
            const float d0 = r.x - s_cen[cx][nn],    d1 = r.y - s_cen[cy][nn];
            const float d2 = r.z - s_cen[cz][nn],    d3 = r.w - s_cen[cw][nn];
            sq0 += d0*d0; sq1 += d1*d1; sq2 += d2*d2; sq3 += d3*d3;
        }
        accv += fmaxf(sqrtf(sq0) - MARGIN_VAR_, 0.f) * (vx ? s_w[cx] : 0.f);
        accv += fmaxf(sqrtf(sq1) - MARGIN_VAR_, 0.f) * (vy ? s_w[cy] : 0.f);
        accv += fmaxf(sqrtf(sq2) - MARGIN_VAR_, 0.f) * (vz ? s_w[cz] : 0.f);
        accv += fmaxf(sqrtf(sq3) - MARGIN_VAR_, 0.f) * (vw ? s_w[cw] : 0.f);
    }

    // =================== chunk 1 ===================
    {
        const bool vx = (lb1.x >= 1 && lb1.x <= C_);
        const bool vy = (lb1.y >= 1 && lb1.y <= C_);
        const bool vz = (lb1.z >= 1 && lb1.z <= C_);
        const bool vw = (lb1.w >= 1 && lb1.w <= C_);
        const int cx = vx ? lb1.x - 1 : 0;
        const int cy = vy ? lb1.y - 1 : 0;
        const int cz = vz ? lb1.z - 1 : 0;
        const int cw = vw ? lb1.w - 1 : 0;

        float sq0 = 0.f, sq1 = 0.f, sq2 = 0.f, sq3 = 0.f;

        // consume va (c1 ch0-3), refill va <- c1 ch8-11
        #pragma unroll
        for (int j = 0; j < 4; ++j) {
            const float4 r = va[j];
            va[j] = *(const float4*)(f1 + (size_t)(8 + j) * P_);
            const float d0 = r.x - s_cen[cx][j],     d1 = r.y - s_cen[cy][j];
            const float d2 = r.z - s_cen[cz][j],     d3 = r.w - s_cen[cw][j];
            sq0 += d0*d0; sq1 += d1*d1; sq2 += d2*d2; sq3 += d3*d3;
        }
        // consume vb (c1 ch4-7), refill vb <- c1 ch12-15
        #pragma unroll
        for (int j = 0; j < 4; ++j) {
            const float4 r = vb[j];
            vb[j] = *(const float4*)(f1 + (size_t)(12 + j) * P_);
            const int nn = 4 + j;
            const float d0 = r.x - s_cen[cx][nn],    d1 = r.y - s_cen[cy][nn];
            const float d2 = r.z - s_cen[cz][nn],    d3 = r.w - s_cen[cw][nn];
            sq0 += d0*d0; sq1 += d1*d1; sq2 += d2*d2; sq3 += d3*d3;
        }
        // consume va (c1 ch8-11)
        #pragma unroll
        for (int j = 0; j < 4; ++j) {
            const float4 r = va[j];
            const int nn = 8 + j;
            const float d0 = r.x - s_cen[cx][nn],    d1 = r.y - s_cen[cy][nn];
            const float d2 = r.z - s_cen[cz][nn],    d3 = r.w - s_cen[cw][nn];
            sq0 += d0*d0; sq1 += d1*d1; sq2 += d2*d2; sq3 += d3*d3;
        }
        // consume vb (c1 ch12-15)
        #pragma unroll
        for (int j = 0; j < 4; ++j) {
            const float4 r = vb[j];
            const int nn = 12 + j;
            const float d0 = r.x - s_cen[cx][nn],    d1 = r.y - s_cen[cy][nn];
            const float d2 = r.z - s_cen[cz][nn],    d3 = r.w - s_cen[cw][nn];
            sq0 += d0*d0; sq1 += d1*d1; sq2 += d2*d2; sq3 += d3*d3;
        }
        accv += fmaxf(sqrtf(sq0) - MARGIN_VAR_, 0.f) * (vx ? s_w[cx] : 0.f);
        accv += fmaxf(sqrtf(sq1) - MARGIN_VAR_, 0.f) * (vy ? s_w[cy] : 0.f);
        accv += fmaxf(sqrtf(sq2) - MARGIN_VAR_, 0.f) * (vz ? s_w[cz] : 0.f);
        accv += fmaxf(sqrtf(sq3) - MARGIN_VAR_, 0.f) * (vw ? s_w[cw] : 0.f);
    }

    #pragma unroll
    for (int off = 32; off > 0; off >>= 1) accv += __shfl_down(accv, off, 64);
    const int lane = tid & 63, wid = tid >> 6;
    if (lane == 0) wsum[wid] = accv;
    __syncthreads();
    if (tid == 0) {
        float t = 0.f;
        #pragma unroll
        for (int w = 0; w < TPB / 64; ++w) t += wsum[w];
        atomicAdd(out, t);   // VAR_WEIGHT = 1
    }
}

// ---------------------------------------------------------------------------
extern "C" void kernel_launch(void* const* d_in, const int* in_sizes, int n_in,
                              void* d_out, int out_size, void* d_ws, size_t ws_size,
                              hipStream_t stream) {
    const float* feat = (const float*)d_in[0];
    const int*   gt   = (const int*)d_in[1];
    float* out = (float*)d_out;
    float* ws  = (float*)d_ws;

    (void)hipMemsetAsync(d_ws, 0, WS_FLOATS * sizeof(float), stream);

    k_accum<<<dim3(B_ * ABPI), dim3(TPB), 0, stream>>>(feat, gt, ws, out);
    k_pull <<<dim3(PNB), dim3(TPB), 0, stream>>>(feat, gt, ws, out);
}

// Round 16
// 58.940 us; speedup vs baseline: 3.9659x; 1.0085x over previous
//
#include <hip/hip_runtime.h>
#include <hip/hip_bf16.h>

// Problem constants (fixed by reference setup_inputs)
constexpr int B_ = 8;
constexpr int N_ = 16;
constexpr int H_ = 368;
constexpr int W_ = 640;
constexpr int P_ = H_ * W_;          // 235520 pixels per image
constexpr int C_ = 12;               // instance ids 1..12
constexpr float MARGIN_VAR_ = 0.5f;
constexpr float MARGIN_DIST_ = 3.0f;

// Workspace layout (floats): sums + counts
constexpr int OFF_SUMS = 0;                      // [B][C][N] feature sums
constexpr int OFF_CNT  = OFF_SUMS + B_*C_*N_;    // [B][C]    pixel counts
constexpr int WS_FLOATS = OFF_CNT + B_*C_;       // 1632 floats

constexpr int TPB = 256;

constexpr int ACH   = 1024;            // k_accum pixels per chunk
constexpr int APAIR = 2 * ACH;         // 2048 px per block (2 chunks)
constexpr int ABPI  = P_ / APAIR;      // 115 (exact)
constexpr int PCH   = 1024;            // k_pull pixels per chunk
constexpr int PPAIR = 2 * PCH;         // 2048 px per block
constexpr int PBPI  = P_ / PPAIR;      // 115 (exact)
constexpr int PNB   = B_ * PBPI;       // 920

constexpr int RS = 1048;               // LDS row stride in shorts (1024 + 24 pad)

typedef short bf16x8 __attribute__((ext_vector_type(8)));   // 8 bf16 (4 VGPR)
typedef float f32x4  __attribute__((ext_vector_type(4)));   // MFMA accumulator

union FragU { int4 i; bf16x8 v; };

__device__ __forceinline__ short f2bf(float f) {
    __hip_bfloat16 h = __float2bfloat16(f);
    return __builtin_bit_cast(short, h);
}

__device__ __forceinline__ int pack_bf2(float x, float y) {
    const unsigned lo = (unsigned short)f2bf(x);
    const unsigned hi = (unsigned short)f2bf(y);
    return (int)(lo | (hi << 16));
}

// ---------------------------------------------------------------------------
// Kernel 1: per-class sums + counts via MFMA. Two 1024-px chunks per block.
// KEY: every LDS exchange (labels + feat tile) is intra-wave — wave w's MFMA
// reads only cols [w*256,(w+1)*256) which wave w's own threads wrote. So the
// main loop runs with ZERO barriers: each wave is an autonomous
// load->convert->MFMA pipeline; waves self-stagger for latency hiding.
// Single barrier before the cross-wave D reduce.
// ---------------------------------------------------------------------------
__global__ __launch_bounds__(TPB) void k_accum(const float* __restrict__ feat,
                                               const int* __restrict__ gt,
                                               float* __restrict__ ws,
                                               float* __restrict__ out) {
    __shared__ int   s_lab8[APAIR / 4];    // 2 KB: 4 labels per int (bytes)
    __shared__ short s_feat[N_ * RS];      // 32.8 KB bf16 tile (1024 px)
    __shared__ float s_red[4][C_];
    __shared__ float s_fin[1024];          // 4 KB

    const int tid  = threadIdx.x;
    const int lane = tid & 63, wid = tid >> 6;
    const int b    = blockIdx.x / ABPI;
    const int pair = blockIdx.x % ABPI;
    const int base = pair * APAIR;

    if (blockIdx.x == 0 && tid == 0) out[0] = 0.f;   // init output before k_pull

    const int*   __restrict__ gb = gt   + (size_t)b * P_ + base;
    const float* __restrict__ fb = feat + (size_t)b * N_ * P_ + base;

    // ---- entry burst: labels (both chunks) + 16 feat float4 (chunk 0) ----
    const int4 lab0 = ((const int4*)gb)[tid];
    const int4 lab1 = ((const int4*)gb)[256 + tid];
    float4 tr[16];
    #pragma unroll
    for (int j = 0; j < 16; ++j)
        tr[j] = *(const float4*)(fb + (size_t)j * P_ + tid * 4);

    s_lab8[tid]       = lab0.x | (lab0.y << 8) | (lab0.z << 16) | (lab0.w << 24);
    s_lab8[256 + tid] = lab1.x | (lab1.y << 8) | (lab1.z << 16) | (lab1.w << 24);

    // ---- per-class counts over both chunks (register-only butterfly) ----
    float cnt[C_];
    #pragma unroll
    for (int c = 0; c < C_; ++c) {
        cnt[c] = ((lab0.x == c+1) ? 1.f : 0.f) + ((lab0.y == c+1) ? 1.f : 0.f)
               + ((lab0.z == c+1) ? 1.f : 0.f) + ((lab0.w == c+1) ? 1.f : 0.f)
               + ((lab1.x == c+1) ? 1.f : 0.f) + ((lab1.y == c+1) ? 1.f : 0.f)
               + ((lab1.z == c+1) ? 1.f : 0.f) + ((lab1.w == c+1) ? 1.f : 0.f);
    }
    #pragma unroll
    for (int off = 32; off > 0; off >>= 1) {
        #pragma unroll
        for (int c = 0; c < C_; ++c) cnt[c] += __shfl_xor(cnt[c], off, 64);
    }
    if (lane == 0) {
        #pragma unroll
        for (int c = 0; c < C_; ++c) s_red[wid][c] = cnt[c];
    }

    // ---- convert chunk 0 -> own LDS stripe; reissue each reg with c1 load ----
    #pragma unroll
    for (int j = 0; j < 16; ++j) {
        const float4 v = tr[j];
        tr[j] = *(const float4*)(fb + (size_t)j * P_ + ACH + tid * 4);  // chunk 1
        int2 w; w.x = pack_bf2(v.x, v.y); w.y = pack_bf2(v.z, v.w);
        *(int2*)(s_feat + j * RS + tid * 4) = w;
    }
    // NO barrier: wave reads only its own stripe below.

    const int n   = lane & 15;              // class-1 (A row) / channel (B col)
    const unsigned cls = (unsigned)(n + 1);
    const int ko  = (lane >> 4) * 8;        // k-octet within 32-px chunk

    f32x4 acc = {0.f, 0.f, 0.f, 0.f};

    // ---- MFMA chunk 0 (chunk-1 loads in flight underneath) ----
    #pragma unroll
    for (int k = 0; k < 8; ++k) {
        const int t = wid * 8 + k;
        const int2 L = *(const int2*)(s_lab8 + t * 8 + (ko >> 2));
        const unsigned u0 = (unsigned)L.x, u1 = (unsigned)L.y;
        FragU au, bu;
        au.i.x = (((u0      ) & 0xFF) == cls ? 0x3F80 : 0) | (((u0 >>  8) & 0xFF) == cls ? 0x3F800000 : 0);
        au.i.y = (((u0 >> 16) & 0xFF) == cls ? 0x3F80 : 0) | (((u0 >> 24)       ) == cls ? 0x3F800000 : 0);
        au.i.z = (((u1      ) & 0xFF) == cls ? 0x3F80 : 0) | (((u1 >>  8) & 0xFF) == cls ? 0x3F800000 : 0);
        au.i.w = (((u1 >> 16) & 0xFF) == cls ? 0x3F80 : 0) | (((u1 >> 24)       ) == cls ? 0x3F800000 : 0);
        bu.v = *(const bf16x8*)(s_feat + n * RS + t * 32 + ko);
        acc = __builtin_amdgcn_mfma_f32_16x16x32_bf16(au.v, bu.v, acc, 0, 0, 0);
    }
    // NO barrier: WAR on own stripe is same-wave in-order.

    // ---- convert chunk 1 -> own stripe (loads arrived during MFMA) ----
    #pragma unroll
    for (int j = 0; j < 16; ++j) {
        int2 w; w.x = pack_bf2(tr[j].x, tr[j].y); w.y = pack_bf2(tr[j].z, tr[j].w);
        *(int2*)(s_feat + j * RS + tid * 4) = w;
    }

    // ---- MFMA chunk 1 ----
    #pragma unroll
    for (int k = 0; k < 8; ++k) {
        const int t = wid * 8 + k;
        const int2 L = *(const int2*)(s_lab8 + 256 + t * 8 + (ko >> 2));
        const unsigned u0 = (unsigned)L.x, u1 = (unsigned)L.y;
        FragU au, bu;
        au.i.x = (((u0      ) & 0xFF) == cls ? 0x3F80 : 0) | (((u0 >>  8) & 0xFF) == cls ? 0x3F800000 : 0);
        au.i.y = (((u0 >> 16) & 0xFF) == cls ? 0x3F80 : 0) | (((u0 >> 24)       ) == cls ? 0x3F800000 : 0);
        au.i.z = (((u1      ) & 0xFF) == cls ? 0x3F80 : 0) | (((u1 >>  8) & 0xFF) == cls ? 0x3F800000 : 0);
        au.i.w = (((u1 >> 16) & 0xFF) == cls ? 0x3F80 : 0) | (((u1 >> 24)       ) == cls ? 0x3F800000 : 0);
        bu.v = *(const bf16x8*)(s_feat + n * RS + t * 32 + ko);
        acc = __builtin_amdgcn_mfma_f32_16x16x32_bf16(au.v, bu.v, acc, 0, 0, 0);
    }

    // ---- single tail (only cross-wave exchange in the kernel) ----
    #pragma unroll
    for (int r = 0; r < 4; ++r) s_fin[wid * 256 + lane * 4 + r] = acc[r];
    __syncthreads();
    if (tid < C_) {
        const float t = s_red[0][tid] + s_red[1][tid] + s_red[2][tid] + s_red[3][tid];
        atomicAdd(&ws[OFF_CNT + b * C_ + tid], t);
    }
    {
        const float sv = s_fin[0 * 256 + tid] + s_fin[1 * 256 + tid]
                       + s_fin[2 * 256 + tid] + s_fin[3 * 256 + tid];
        const int elane = tid >> 2, r = tid & 3;
        const int row = (elane >> 4) * 4 + r;   // class (D row)
        const int col = elane & 15;             // channel (D col)
        if (row < C_)
            atomicAdd(&ws[OFF_SUMS + ((size_t)b * C_ + row) * N_ + col], sv);
    }
}

// ---------------------------------------------------------------------------
// Kernel 2: pull + push. Two 1024-px chunks per block (R15-verbatim).
// ---------------------------------------------------------------------------
__global__ __launch_bounds__(TPB) void k_pull(const float* __restrict__ feat,
                                              const int* __restrict__ gt,
                                              const float* __restrict__ ws,
                                              float* __restrict__ out) {
    __shared__ float s_cen[C_][N_ + 1];
    __shared__ float s_w[C_];
    __shared__ float s_cntv[B_ * C_];
    __shared__ float red[TPB];
    __shared__ float wsum[TPB / 64];

    const int tid = threadIdx.x;
    // reverse round order, keep blockIdx%8 (same-XCD) alignment
    const int g2   = (PNB / 8 - 1 - (int)(blockIdx.x >> 3)) * 8 + (blockIdx.x & 7);
    const int b    = g2 / PBPI;
    const int pair = g2 % PBPI;
    const int base = pair * PPAIR;

    const int*   __restrict__ gb = gt + (size_t)b * P_ + base;
    const float* __restrict__ f0 = feat + (size_t)b * N_ * P_ + base + tid * 4;
    const float* __restrict__ f1 = f0 + PCH;

    // ---- issue labels + first 8 chunk-0 channel loads (fly during preamble) ----
    const int4 lb0 = ((const int4*)gb)[tid];
    const int4 lb1 = ((const int4*)gb)[256 + tid];
    float4 va[4], vb[4];
    #pragma unroll
    for (int j = 0; j < 4; ++j) va[j] = *(const float4*)(f0 + (size_t)j * P_);
    #pragma unroll
    for (int j = 0; j < 4; ++j) vb[j] = *(const float4*)(f0 + (size_t)(4 + j) * P_);

    // ---- preamble: counts -> n_inst, centers, weights ----
    if (tid < B_ * C_) s_cntv[tid] = ws[OFF_CNT + tid];
    __syncthreads();

    float n_inst = 0.f;
    #pragma unroll 8
    for (int i = 0; i < B_ * C_; ++i) n_inst += (s_cntv[i] > 0.f) ? 1.f : 0.f;

    if (tid < C_ * N_) {
        const int c = tid >> 4, n = tid & 15;
        const float ct = s_cntv[b * C_ + c];
        s_cen[c][n] = ws[OFF_SUMS + ((size_t)b * C_ + c) * N_ + n] / fmaxf(ct, 1.f);
    }
    if (tid < C_) {
        const float ct = s_cntv[b * C_ + tid];
        s_w[tid] = (ct > 0.f && n_inst > 0.f) ? 1.0f / (ct * n_inst) : 0.f;
    }
    __syncthreads();

    // ---- push loss: once per image (pair==0 block) ----
    if (pair == 0) {
        float ps = 0.f;
        if (tid < C_ * C_) {
            const int i = tid / C_, j = tid % C_;
            if (i != j && s_cntv[b * C_ + i] > 0.f && s_cntv[b * C_ + j] > 0.f) {
                float sq = 0.f;
                #pragma unroll
                for (int n = 0; n < N_; ++n) {
                    const float d = s_cen[i][n] - s_cen[j][n];
                    sq += d * d;
                }
                ps = fmaxf(2.f * MARGIN_DIST_ - sqrtf(sq), 0.f);
            }
        }
        red[tid] = ps;
        __syncthreads();
        for (int s = TPB / 2; s > 0; s >>= 1) {
            if (tid < s) red[tid] += red[tid + s];
            __syncthreads();
        }
        if (tid == 0) {
            float np = 0.f;
            for (int bb_ = 0; bb_ < B_; ++bb_) {
                int k = 0;
                for (int c = 0; c < C_; ++c) k += (s_cntv[bb_ * C_ + c] > 0.f) ? 1 : 0;
                np += (float)(k * (k - 1));
            }
            if (np > 0.f) atomicAdd(out, red[0] / np);   // DIST_WEIGHT = 1
        }
    }

    float accv = 0.f;

    // =================== chunk 0 ===================
    {
        const bool vx = (lb0.x >= 1 && lb0.x <= C_);
        const bool vy = (lb0.y >= 1 && lb0.y <= C_);
        const bool vz = (lb0.z >= 1 && lb0.z <= C_);
        const bool vw = (lb0.w >= 1 && lb0.w <= C_);
        const int cx = vx ? lb0.x - 1 : 0;
        const int cy = vy ? lb0.y - 1 : 0;
        const int cz = vz ? lb0.z - 1 : 0;
        const int cw = vw ? lb0.w - 1 : 0;

        float sq0 = 0.f, sq1 = 0.f, sq2 = 0.f, sq3 = 0.f;

        #pragma unroll
        for (int j = 0; j < 4; ++j) {
            const float4 r = va[j];
            va[j] = *(const float4*)(f0 + (size_t)(8 + j) * P_);
            const float d0 = r.x - s_cen[cx][j],     d1 = r.y - s_cen[cy][j];
            const float d2 = r.z - s_cen[cz][j],     d3 = r.w - s_cen[cw][j];
            sq0 += d0*d0; sq1 += d1*d1; sq2 += d2*d2; sq3 += d3*d3;
        }
        #pragma unroll
        for (int j = 0; j < 4; ++j) {
            const float4 r = vb[j];
            vb[j] = *(const float4*)(f0 + (size_t)(12 + j) * P_);
            const int nn = 4 + j;
            const float d0 = r.x - s_cen[cx][nn],    d1 = r.y - s_cen[cy][nn];
            const float d2 = r.z - s_cen[cz][nn],    d3 = r.w - s_cen[cw][nn];
            sq0 += d0*d0; sq1 += d1*d1; sq2 += d2*d2; sq3 += d3*d3;
        }
        #pragma unroll
        for (int j = 0; j < 4; ++j) {
            const float4 r = va[j];
            va[j] = *(const float4*)(f1 + (size_t)j * P_);
            const int nn = 8 + j;
            const float d0 = r.x - s_cen[cx][nn],    d1 = r.y - s_cen[cy][nn];
            const float d2 = r.z - s_cen[cz][nn],    d3 = r.w - s_cen[cw][nn];
            sq0 += d0*d0; sq1 += d1*d1; sq2 += d2*d2; sq3 += d3*d3;
        }
        #pragma unroll
        for (int j = 0; j < 4; ++j) {
            const float4 r = vb[j];
            vb[j] = *(const float4*)(f1 + (size_t)(4 + j) * P_);
            const int nn = 12 + j;
            const float d0 = r.x - s_cen[cx][nn],    d1 = r.y - s_cen[cy][nn];
            const float d2 = r.z - s_cen[cz][nn],    d3 = r.w - s_cen[cw][nn];
            sq0 += d0*d0; sq1 += d1*d1; sq2 += d2*d2; sq3 += d3*d3;
        }
        accv += fmaxf(sqrtf(sq0) - MARGIN_VAR_, 0.f) * (vx ? s_w[cx] : 0.f);
        accv += fmaxf(sqrtf(sq1) - MARGIN_VAR_, 0.f) * (vy ? s_w[cy] : 0.f);
        accv += fmaxf(sqrtf(sq2) - MARGIN_VAR_, 0.f) * (vz ? s_w[cz] : 0.f);
        accv += fmaxf(sqrtf(sq3) - MARGIN_VAR_, 0.f) * (vw ? s_w[cw] : 0.f);
    }

    // =================== chunk 1 ===================
    {
        const bool vx = (lb1.x >= 1 && lb1.x <= C_);
        const bool vy = (lb1.y >= 1 && lb1.y <= C_);
        const bool vz = (lb1.z >= 1 && lb1.z <= C_);
        const bool vw = (lb1.w >= 1 && lb1.w <= C_);
        const int cx = vx ? lb1.x - 1 : 0;
        const int cy = vy ? lb1.y - 1 : 0;
        const int cz = vz ? lb1.z - 1 : 0;
        const int cw = vw ? lb1.w - 1 : 0;

        float sq0 = 0.f, sq1 = 0.f, sq2 = 0.f, sq3 = 0.f;

        #pragma unroll
        for (int j = 0; j < 4; ++j) {
            const float4 r = va[j];
            va[j] = *(const float4*)(f1 + (size_t)(8 + j) * P_);
            const float d0 = r.x - s_cen[cx][j],     d1 = r.y - s_cen[cy][j];
            const float d2 = r.z - s_cen[cz][j],     d3 = r.w - s_cen[cw][j];
            sq0 += d0*d0; sq1 += d1*d1; sq2 += d2*d2; sq3 += d3*d3;
        }
        #pragma unroll
        for (int j = 0; j < 4; ++j) {
            const float4 r = vb[j];
            vb[j] = *(const float4*)(f1 + (size_t)(12 + j) * P_);
            const int nn = 4 + j;
            const float d0 = r.x - s_cen[cx][nn],    d1 = r.y - s_cen[cy][nn];
            const float d2 = r.z - s_cen[cz][nn],    d3 = r.w - s_cen[cw][nn];
            sq0 += d0*d0; sq1 += d1*d1; sq2 += d2*d2; sq3 += d3*d3;
        }
        #pragma unroll
        for (int j = 0; j < 4; ++j) {
            const float4 r = va[j];
            const int nn = 8 + j;
            const float d0 = r.x - s_cen[cx][nn],    d1 = r.y - s_cen[cy][nn];
            const float d2 = r.z - s_cen[cz][nn],    d3 = r.w - s_cen[cw][nn];
            sq0 += d0*d0; sq1 += d1*d1; sq2 += d2*d2; sq3 += d3*d3;
        }
        #pragma unroll
        for (int j = 0; j < 4; ++j) {
            const float4 r = vb[j];
            const int nn = 12 + j;
            const float d0 = r.x - s_cen[cx][nn],    d1 = r.y - s_cen[cy][nn];
            const float d2 = r.z - s_cen[cz][nn],    d3 = r.w - s_cen[cw][nn];
            sq0 += d0*d0; sq1 += d1*d1; sq2 += d2*d2; sq3 += d3*d3;
        }
        accv += fmaxf(sqrtf(sq0) - MARGIN_VAR_, 0.f) * (vx ? s_w[cx] : 0.f);
        accv += fmaxf(sqrtf(sq1) - MARGIN_VAR_, 0.f) * (vy ? s_w[cy] : 0.f);
        accv += fmaxf(sqrtf(sq2) - MARGIN_VAR_, 0.f) * (vz ? s_w[cz] : 0.f);
        accv += fmaxf(sqrtf(sq3) - MARGIN_VAR_, 0.f) * (vw ? s_w[cw] : 0.f);
    }

    #pragma unroll
    for (int off = 32; off > 0; off >>= 1) accv += __shfl_down(accv, off, 64);
    const int lane = tid & 63, wid = tid >> 6;
    if (lane == 0) wsum[wid] = accv;
    __syncthreads();
    if (tid == 0) {
        float t = 0.f;
        #pragma unroll
        for (int w = 0; w < TPB / 64; ++w) t += wsum[w];
        atomicAdd(out, t);   // VAR_WEIGHT = 1
    }
}

// ---------------------------------------------------------------------------
extern "C" void kernel_launch(void* const* d_in, const int* in_sizes, int n_in,
                              void* d_out, int out_size, void* d_ws, size_t ws_size,
                              hipStream_t stream) {
    const float* feat = (const float*)d_in[0];
    const int*   gt   = (const int*)d_in[1];
    float* out = (float*)d_out;
    float* ws  = (float*)d_ws;

    (void)hipMemsetAsync(d_ws, 0, WS_FLOATS * sizeof(float), stream);

    k_accum<<<dim3(B_ * ABPI), dim3(TPB), 0, stream>>>(feat, gt, ws, out);
    k_pull <<<dim3(PNB), dim3(TPB), 0, stream>>>(feat, gt, ws, out);
}